// Round 2
// baseline (781.965 us; speedup 1.0000x reference)
//
#include <hip/hip_runtime.h>
#include <hip/hip_bf16.h>

#define H_DIM 1024
#define I_DIM 2752   // = 43 * 64
#define T_TOK 4096
#define NE 8
#define NROWS (3 * T_TOK)   // 8192 routed pairs + 4096 shared

typedef __bf16 bf16;
typedef __bf16 bf16x8 __attribute__((ext_vector_type(8)));
typedef __bf16 bf16x4 __attribute__((ext_vector_type(4)));
typedef float f32x4 __attribute__((ext_vector_type(4)));

// ---- sizes (elements) ----
constexpr size_t N_X = (size_t)T_TOK * H_DIM;        // 4,194,304
constexpr size_t N_W = (size_t)NE * I_DIM * H_DIM;   // 22,544,384
constexpr size_t N_S = (size_t)I_DIM * H_DIM;        // 2,818,048
constexpr size_t N_H = (size_t)NROWS * I_DIM;        // 33,816,576

// ---- workspace layout (bytes) ----
constexpr size_t WS_CNT  = 0;
constexpr size_t WS_OFFS = 64;
constexpr size_t WS_COMB = 256;                                  // T*NE fp32 (slow path only)
constexpr size_t WS_TOKEP = WS_COMB + (size_t)T_TOK * NE * 4;    // int4 per token
constexpr size_t WS_TOKW  = WS_TOKEP + (size_t)T_TOK * 16;       // float2 per token
constexpr size_t WS_LIST  = WS_TOKW + (size_t)T_TOK * 8;
constexpr size_t WS_XB   = WS_LIST + (size_t)NE * T_TOK * 4;
constexpr size_t WS_WGB  = WS_XB  + N_X * 2;
constexpr size_t WS_WUB  = WS_WGB + N_W * 2;
constexpr size_t WS_WDB  = WS_WUB + N_W * 2;
constexpr size_t WS_WSGB = WS_WDB + N_W * 2;
constexpr size_t WS_WSUB = WS_WSGB + N_S * 2;
constexpr size_t WS_WSDB = WS_WSUB + N_S * 2;
constexpr size_t WS_HF   = WS_WSDB + N_S * 2;
constexpr size_t WS_NEED = WS_HF + N_H * 2;          // ~218 MB
// eo[NROWS][H_DIM] bf16 (24 MB) aliases wgb (45 MB) — wgb is dead after ffn1
constexpr size_t WS_EO   = WS_WGB;
// slow-path h (fallback if ws too small)
constexpr size_t WS_HS   = WS_XB;

// direct global->LDS, 16B per lane. LDS dst is wave-uniform base; HW scatters lane*16.
__device__ inline void gll16(const bf16* g, bf16* l) {
    __builtin_amdgcn_global_load_lds(
        (const __attribute__((address_space(1))) unsigned int*)g,
        (__attribute__((address_space(3))) unsigned int*)l, 16, 0, 0);
}

// counted-vmcnt wait: never drain to 0 in the main loop (T4).
#define VM_WAIT8 asm volatile("s_waitcnt vmcnt(8)" ::: "memory")

// ---------------- gating (coalesced; fuses x -> bf16 conversion) ----------------
__global__ void gate_kernel(const float* __restrict__ x, const float* __restrict__ gw,
                            float* __restrict__ comb, int4* __restrict__ tok_ep,
                            float2* __restrict__ tok_w, int* __restrict__ cnt,
                            int* __restrict__ list, bf16* __restrict__ xb) {
    int t = blockIdx.x;
    int lane = threadIdx.x;   // 64
    const float* xr = x + (size_t)t * H_DIM;
    float4 xv[4];
    for (int j = 0; j < 4; ++j) xv[j] = *(const float4*)(xr + lane * 4 + j * 256);
    float p[NE] = {};
    for (int e = 0; e < NE; ++e) {
        const float* wr = gw + (size_t)e * H_DIM;
        for (int j = 0; j < 4; ++j) {
            float4 wv = *(const float4*)(wr + lane * 4 + j * 256);
            p[e] += xv[j].x * wv.x + xv[j].y * wv.y + xv[j].z * wv.z + xv[j].w * wv.w;
        }
    }
    for (int j = 0; j < 4; ++j) {
        bf16x4 b = { (bf16)xv[j].x, (bf16)xv[j].y, (bf16)xv[j].z, (bf16)xv[j].w };
        *(bf16x4*)(xb + (size_t)t * H_DIM + lane * 4 + j * 256) = b;
    }
    for (int o = 32; o >= 1; o >>= 1)
        for (int e = 0; e < NE; ++e) p[e] += __shfl_xor(p[e], o);
    if (lane == 0) {
        float m = p[0];
        for (int j = 1; j < NE; ++j) m = fmaxf(m, p[j]);
        float s[NE], Z = 0.f;
        for (int j = 0; j < NE; ++j) { s[j] = expf(p[j] - m); Z += s[j]; }
        for (int j = 0; j < NE; ++j) s[j] /= Z;
        int i0 = 0;
        for (int j = 1; j < NE; ++j) if (s[j] > s[i0]) i0 = j;
        int i1 = (i0 == 0) ? 1 : 0;
        for (int j = 0; j < NE; ++j) if (j != i0 && s[j] > s[i1]) i1 = j;
        float d = s[i0] + s[i1] + 1e-20f;
        float w0 = s[i0] / d, w1 = s[i1] / d;
        for (int j = 0; j < NE; ++j) comb[t * NE + j] = 0.f;
        comb[t * NE + i0] = w0;
        comb[t * NE + i1] = w1;
        int p0 = atomicAdd(&cnt[i0], 1); list[i0 * T_TOK + p0] = t;
        int p1 = atomicAdd(&cnt[i1], 1); list[i1 * T_TOK + p1] = t;
        tok_ep[t] = make_int4(i0, p0, i1, p1);
        tok_w[t] = make_float2(w0, w1);
    }
}

__global__ void offs_kernel(const int* __restrict__ cnt, int* __restrict__ offs) {
    if (threadIdx.x == 0) {
        int a = 0;
        for (int e = 0; e < NE; ++e) { offs[e] = a; a += cnt[e]; }
        offs[NE] = a;   // routed total; shared rows start here
    }
}

// ---------------- fp32 -> bf16 conversion ----------------
__device__ inline void cvt8(const float* __restrict__ s, bf16* __restrict__ d) {
    float4 a = ((const float4*)s)[0];
    float4 b = ((const float4*)s)[1];
    bf16x8 v = { (bf16)a.x, (bf16)a.y, (bf16)a.z, (bf16)a.w,
                 (bf16)b.x, (bf16)b.y, (bf16)b.z, (bf16)b.w };
    *(bf16x8*)d = v;
}

// converts ffn1's weights only (w_down converted inside ffn1's role blocks)
__global__ void convert_kernel(const float* __restrict__ wg, const float* __restrict__ wu,
                               const float* __restrict__ wsg, const float* __restrict__ wsu,
                               bf16* wgb, bf16* wub, bf16* wsgb, bf16* wsub) {
    size_t i = ((size_t)blockIdx.x * 256 + threadIdx.x) * 8;
    if (i < N_W) { cvt8(wg + i, wgb + i); return; }
    i -= N_W;
    if (i < N_W) { cvt8(wu + i, wub + i); return; }
    i -= N_W;
    if (i < N_S) { cvt8(wsg + i, wsgb + i); return; }
    i -= N_S;
    if (i < N_S) { cvt8(wsu + i, wsub + i); }
}

#define BM 128
#define MT_MAX 104
#define BK 64
#define BK2 32
#define NH1 (H_DIM / BK2)   // 32 half-steps
#define NH2 (I_DIM / BK2)   // 86 half-steps

// supertile map: expert-major; within expert, groups of 8 m-tiles x nt_cnt n-tiles,
// msub fastest (8 consecutive work items share a B n-tile; a group of 8*nt_cnt items
// touches only an 8-m-tile A-slab + nt_cnt B-tiles).
__device__ inline bool map_super(const int* cnt, int bx, int nt_cnt,
                                 int& expert, int& mtile, int& nt, int& count) {
    for (int e = 0; e <= NE; ++e) {
        int c = (e < NE) ? cnt[e] : T_TOK;
        int tiles = (c + BM - 1) / BM;
        int blocks = tiles * nt_cnt;
        if (bx < blocks) {
            int full = tiles & ~7;              // m-tiles in full groups of 8
            int fullblocks = full * nt_cnt;
            int mg0, gsz, rem;
            if (bx < fullblocks) { mg0 = (bx / (nt_cnt * 8)) * 8; gsz = 8; rem = bx % (nt_cnt * 8); }
            else                 { mg0 = full; gsz = tiles - full; rem = bx - fullblocks; }
            nt = rem / gsz;
            mtile = mg0 + rem % gsz;
            expert = e; count = c;
            return true;
        }
        bx -= blocks;
    }
    return false;
}

// total active GEMM blocks (must match map_super's walk)
__device__ inline int active_blocks(const int* cnt, int nt_cnt) {
    int t = 0;
    for (int e = 0; e < NE; ++e) t += (cnt[e] + BM - 1) / BM;
    return (t + T_TOK / BM) * nt_cnt;
}

// bijective XCD-chunked swizzle (m204 variant): block with hw XCD = bx%8 gets a
// CONTIGUOUS chunk of the supertile sequence, so msub-neighbors sharing a B-tile
// land on the SAME XCD's L2.
__device__ inline int xcd_chunk(int bx, int n) {
    int q = n >> 3, r = n & 7;
    int x = bx & 7, o = bx >> 3;
    return (x < r ? x * (q + 1) : r * (q + 1) + (x - r) * q) + o;
}

// linear map (slow path)
__device__ inline bool map_tile(const int* cnt, int mt, int bm,
                                int& expert, int& mtile, int& count) {
    for (int e = 0; e <= NE; ++e) {
        int c = (e < NE) ? cnt[e] : T_TOK;
        int tiles = (c + bm - 1) / bm;
        if (mt < tiles) { expert = e; mtile = mt; count = c; return true; }
        mt -= tiles;
    }
    return false;
}

// ---------------- fast GEMM1: h = silu(x@Wg^T) * (x@Wu^T) ----------------
// 3-deep pipeline at BK2=32 granularity: issue stage(t+2), counted vmcnt(8)
// (waits stage(t) only; stages t+1,t+2 stay in flight ACROSS the barriers),
// raw s_barrier pair per iteration. LDS 48KB (3 bufs) -> 3 blocks/CU.
// Swizzle: LDS[r][g16] holds global 16B-group g16 ^ ((r>>1)&3) (involution,
// pre-applied on the per-lane global source address for global_load_lds).
#define BN1 64
#define NT1 (I_DIM / BN1)   // 43
#define CONV1_BLKS 3096     // (N_W + N_S) / (256*32) exactly; multiple of 8

__global__ __launch_bounds__(256) void ffn1_fast(
    const bf16* __restrict__ xb, const bf16* __restrict__ wgb,
    const bf16* __restrict__ wub, const bf16* __restrict__ wsgb,
    const bf16* __restrict__ wsub, const int* __restrict__ cnt,
    const int* __restrict__ offs, const int* __restrict__ list,
    bf16* __restrict__ h,
    const float* __restrict__ wd_f, const float* __restrict__ wsd_f,
    bf16* __restrict__ wdb, bf16* __restrict__ wsdb) {
    if (blockIdx.x < CONV1_BLKS) {
        size_t base = (size_t)blockIdx.x * 8192 + (size_t)threadIdx.x * 8;
        for (int j = 0; j < 4; ++j) {
            size_t i = base + (size_t)j * 2048;
            if (i < N_W) cvt8(wd_f + i, wdb + i);
            else         cvt8(wsd_f + (i - N_W), wsdb + (i - N_W));
        }
        return;
    }
    int bx = blockIdx.x - CONV1_BLKS;   // CONV1_BLKS % 8 == 0, so bx%8 == hw XCD
    int nact = active_blocks(cnt, NT1);
    if (bx >= nact) return;
    bx = xcd_chunk(bx, nact);
    int expert, mtile, nt, count;
    if (!map_super(cnt, bx, NT1, expert, mtile, nt, count)) return;
    int rowbase = offs[expert];
    const bf16* wg = (expert < NE) ? (wgb + (size_t)expert * N_S) : wsgb;
    const bf16* wu = (expert < NE) ? (wub + (size_t)expert * N_S) : wsub;

    __shared__ bf16 As[3][BM][BK2];    // 24 KB
    __shared__ bf16 Bg[3][BN1][BK2];   // 12 KB
    __shared__ bf16 Bu[3][BN1][BK2];   // 12 KB

    int tid = threadIdx.x;
    int lane = tid & 63, wid = tid >> 6;
    int wm = wid >> 1, wn = wid & 1;
    int lr = lane & 15, lq = lane >> 4;
    int l4 = lane >> 2, c4 = lane & 3;
    int c4s = c4 ^ ((lane >> 3) & 3);   // pre-swizzled source 16B-group
    int iN = nt * BN1;

    const bf16* aptr0;
    const bf16* aptr1;
    {
        int r0 = wid * 32 + l4;
        int m0 = mtile * BM + r0;
        int t0 = 0;
        if (m0 < count) t0 = (expert < NE) ? list[expert * T_TOK + m0] : m0;
        aptr0 = xb + (size_t)t0 * H_DIM + c4s * 8;
        int r1 = wid * 32 + 16 + l4;
        int m1 = mtile * BM + r1;
        int t1 = 0;
        if (m1 < count) t1 = (expert < NE) ? list[expert * T_TOK + m1] : m1;
        aptr1 = xb + (size_t)t1 * H_DIM + c4s * 8;
    }
    int rb = wid * 16 + l4;
    const bf16* gp = wg + (size_t)(iN + rb) * H_DIM + c4s * 8;
    const bf16* up = wu + (size_t)(iN + rb) * H_DIM + c4s * 8;

    int fragoff = (lq ^ ((lr >> 1) & 3)) << 3;
    int arow[4], brow[2];
    for (int mi = 0; mi < 4; ++mi) arow[mi] = (wm * 64 + mi * 16 + lr) * BK2 + fragoff;
    for (int ni = 0; ni < 2; ++ni) brow[ni] = (wn * 32 + ni * 16 + lr) * BK2 + fragoff;

    f32x4 accg[4][2] = {};
    f32x4 accu[4][2] = {};

    auto stage = [&](bf16* Ad, bf16* Gd, bf16* Ud, int hs) {   // 4 gll16 per thread
        int off = hs * BK2;
        gll16(aptr0 + off, Ad + (wid * 32) * BK2);
        gll16(aptr1 + off, Ad + (wid * 32 + 16) * BK2);
        gll16(gp + off, Gd + (wid * 16) * BK2);
        gll16(up + off, Ud + (wid * 16) * BK2);
    };

    bf16 *A0 = &As[0][0][0], *A1 = &As[1][0][0], *A2 = &As[2][0][0];
    bf16 *G0 = &Bg[0][0][0], *G1 = &Bg[1][0][0], *G2 = &Bg[2][0][0];
    bf16 *U0 = &Bu[0][0][0], *U1 = &Bu[1][0][0], *U2 = &Bu[2][0][0];
    stage(A0, G0, U0, 0);
    stage(A1, G1, U1, 1);
    for (int hs = 0; hs < NH1; ++hs) {
        int hs2 = (hs + 2 < NH1) ? hs + 2 : NH1 - 1;   // clamp keeps counts uniform
        stage(A2, G2, U2, hs2);
        VM_WAIT8;                        // stage(hs) landed; hs+1,hs+2 in flight
        __builtin_amdgcn_s_barrier();    // all waves' stage(hs) landed
        __builtin_amdgcn_sched_barrier(0);
        bf16x8 af[4], bgf[2], buf_[2];
        for (int mi = 0; mi < 4; ++mi) af[mi] = *(const bf16x8*)(A0 + arow[mi]);
        for (int ni = 0; ni < 2; ++ni) {
            bgf[ni]  = *(const bf16x8*)(G0 + brow[ni]);
            buf_[ni] = *(const bf16x8*)(U0 + brow[ni]);
        }
        __builtin_amdgcn_s_setprio(1);
        for (int mi = 0; mi < 4; ++mi)
            for (int ni = 0; ni < 2; ++ni) {
                accg[mi][ni] = __builtin_amdgcn_mfma_f32_16x16x32_bf16(af[mi], bgf[ni], accg[mi][ni], 0, 0, 0);
                accu[mi][ni] = __builtin_amdgcn_mfma_f32_16x16x32_bf16(af[mi], buf_[ni], accu[mi][ni], 0, 0, 0);
            }
        __builtin_amdgcn_s_setprio(0);
        __builtin_amdgcn_s_barrier();    // readers done; A0's buffer reusable next iter
        bf16* tp;
        tp = A0; A0 = A1; A1 = A2; A2 = tp;
        tp = G0; G0 = G1; G1 = G2; G2 = tp;
        tp = U0; U0 = U1; U1 = U2; U2 = tp;
    }
    for (int mi = 0; mi < 4; ++mi)
        for (int ni = 0; ni < 2; ++ni)
            for (int r2 = 0; r2 < 4; ++r2) {
                int row = wm * 64 + mi * 16 + lq * 4 + r2;
                int m = mtile * BM + row;
                if (m >= count) continue;
                float g = accg[mi][ni][r2], u = accu[mi][ni][r2];
                float hv = g / (1.f + expf(-g)) * u;
                int col = iN + wn * 32 + ni * 16 + lr;
                h[(size_t)(rowbase + m) * I_DIM + col] = (bf16)hv;
            }
}

// ---------------- fast GEMM2: eo = h @ Wd^T, 128x128 tiles, 3-deep pipeline ----------------
#define BN2 128
#define NT2 (H_DIM / BN2)   // 8

__global__ __launch_bounds__(256) void ffn2_fast(
    const bf16* __restrict__ h, const bf16* __restrict__ wdb,
    const bf16* __restrict__ wsdb, const int* __restrict__ cnt,
    const int* __restrict__ offs, bf16* __restrict__ eo) {
    int nact = active_blocks(cnt, NT2);
    int bx = blockIdx.x;
    if (bx >= nact) return;
    bx = xcd_chunk(bx, nact);
    int expert, mtile, nt, count;
    if (!map_super(cnt, bx, NT2, expert, mtile, nt, count)) return;
    int rowbase = offs[expert];
    const bf16* wd = (expert < NE) ? (wdb + (size_t)expert * N_S) : wsdb;

    __shared__ bf16 As[3][BM][BK2];    // 24 KB
    __shared__ bf16 Bs[3][BN2][BK2];   // 24 KB

    int tid = threadIdx.x;
    int lane = tid & 63, wid = tid >> 6;
    int wm = wid >> 1, wn = wid & 1;
    int lr = lane & 15, lq = lane >> 4;
    int l4 = lane >> 2, c4 = lane & 3;
    int c4s = c4 ^ ((lane >> 3) & 3);
    int hN = nt * BN2;

    const bf16* aptr0;
    const bf16* aptr1;
    {
        int r0 = wid * 32 + l4;
        int m0 = mtile * BM + r0;
        size_t h0 = (size_t)rowbase + ((m0 < count) ? m0 : 0);
        aptr0 = h + h0 * I_DIM + c4s * 8;
        int r1 = wid * 32 + 16 + l4;
        int m1 = mtile * BM + r1;
        size_t h1 = (size_t)rowbase + ((m1 < count) ? m1 : 0);
        aptr1 = h + h1 * I_DIM + c4s * 8;
    }
    const bf16* bptr0;
    const bf16* bptr1;
    {
        int r0 = wid * 32 + l4;
        bptr0 = wd + (size_t)(hN + r0) * I_DIM + c4s * 8;
        int r1 = wid * 32 + 16 + l4;
        bptr1 = wd + (size_t)(hN + r1) * I_DIM + c4s * 8;
    }

    int fragoff = (lq ^ ((lr >> 1) & 3)) << 3;
    int arow[4], brow[4];
    for (int mi = 0; mi < 4; ++mi) arow[mi] = (wm * 64 + mi * 16 + lr) * BK2 + fragoff;
    for (int ni = 0; ni < 4; ++ni) brow[ni] = (wn * 64 + ni * 16 + lr) * BK2 + fragoff;

    f32x4 acc[4][4] = {};

    auto stage = [&](bf16* Ad, bf16* Bd, int hs) {   // 4 gll16 per thread
        int off = hs * BK2;
        gll16(aptr0 + off, Ad + (wid * 32) * BK2);
        gll16(aptr1 + off, Ad + (wid * 32 + 16) * BK2);
        gll16(bptr0 + off, Bd + (wid * 32) * BK2);
        gll16(bptr1 + off, Bd + (wid * 32 + 16) * BK2);
    };

    bf16 *A0 = &As[0][0][0], *A1 = &As[1][0][0], *A2 = &As[2][0][0];
    bf16 *B0 = &Bs[0][0][0], *B1 = &Bs[1][0][0], *B2 = &Bs[2][0][0];
    stage(A0, B0, 0);
    stage(A1, B1, 1);
    for (int hs = 0; hs < NH2; ++hs) {
        int hs2 = (hs + 2 < NH2) ? hs + 2 : NH2 - 1;
        stage(A2, B2, hs2);
        VM_WAIT8;
        __builtin_amdgcn_s_barrier();
        __builtin_amdgcn_sched_barrier(0);
        bf16x8 af[4], bf2[4];
        for (int mi = 0; mi < 4; ++mi) af[mi] = *(const bf16x8*)(A0 + arow[mi]);
        for (int ni = 0; ni < 4; ++ni) bf2[ni] = *(const bf16x8*)(B0 + brow[ni]);
        __builtin_amdgcn_s_setprio(1);
        for (int mi = 0; mi < 4; ++mi)
            for (int ni = 0; ni < 4; ++ni)
                acc[mi][ni] = __builtin_amdgcn_mfma_f32_16x16x32_bf16(af[mi], bf2[ni], acc[mi][ni], 0, 0, 0);
        __builtin_amdgcn_s_setprio(0);
        __builtin_amdgcn_s_barrier();
        bf16* tp;
        tp = A0; A0 = A1; A1 = A2; A2 = tp;
        tp = B0; B0 = B1; B1 = B2; B2 = tp;
    }
    for (int mi = 0; mi < 4; ++mi)
        for (int ni = 0; ni < 4; ++ni)
            for (int r2 = 0; r2 < 4; ++r2) {
                int row = wm * 64 + mi * 16 + lq * 4 + r2;
                int m = mtile * BM + row;
                if (m >= count) continue;
                int col = hN + wn * 64 + ni * 16 + lr;
                eo[(size_t)(rowbase + m) * H_DIM + col] = (bf16)acc[mi][ni][r2];
            }
}

// ---------------- combine: out[t] = w0*eo[r0] + w1*eo[r1] + eo[shared_t] ----------------
__global__ __launch_bounds__(256) void combine_kernel(
    const bf16* __restrict__ eo, const int* __restrict__ offs,
    const int4* __restrict__ tok_ep, const float2* __restrict__ tok_w,
    float* __restrict__ out) {
    int t = blockIdx.x;
    int c = threadIdx.x * 4;
    int4 ep = tok_ep[t];
    float2 w = tok_w[t];
    size_t r0 = (size_t)(offs[ep.x] + ep.y) * H_DIM + c;
    size_t r1 = (size_t)(offs[ep.z] + ep.w) * H_DIM + c;
    size_t rs = (size_t)(offs[NE] + t) * H_DIM + c;
    bf16x4 a = *(const bf16x4*)(eo + r0);
    bf16x4 b = *(const bf16x4*)(eo + r1);
    bf16x4 s = *(const bf16x4*)(eo + rs);
    float4 o;
    o.x = w.x * (float)a[0] + w.y * (float)b[0] + (float)s[0];
    o.y = w.x * (float)a[1] + w.y * (float)b[1] + (float)s[1];
    o.z = w.x * (float)a[2] + w.y * (float)b[2] + (float)s[2];
    o.w = w.x * (float)a[3] + w.y * (float)b[3] + (float)s[3];
    *(float4*)(out + (size_t)t * H_DIM + c) = o;
}

// ================= slow fallback (fp32 staging, atomics) =================
#define SBN1 64
#define SNT1 (I_DIM / SBN1)
#define SBN2 64
#define SNT2 (H_DIM / SBN2)

__global__ __launch_bounds__(256) void ffn1_slow(
    const float* __restrict__ x, const float* __restrict__ w_gate,
    const float* __restrict__ w_up, const float* __restrict__ wsg,
    const float* __restrict__ wsu, const int* __restrict__ cnt,
    const int* __restrict__ offs, const int* __restrict__ list,
    bf16* __restrict__ h) {
    int nt = blockIdx.x % SNT1;
    int mt = blockIdx.x / SNT1;
    int expert, mtile, count;
    if (!map_tile(cnt, mt, BM, expert, mtile, count)) return;
    int rowbase = offs[expert];
    const float* wg = (expert < NE) ? (w_gate + (size_t)expert * N_S) : wsg;
    const float* wu = (expert < NE) ? (w_up + (size_t)expert * N_S) : wsu;
    __shared__ bf16 As[BM][BK + 8];
    __shared__ bf16 Bg[SBN1][BK + 8];
    __shared__ bf16 Bu[SBN1][BK + 8];
    int tid = threadIdx.x;
    int lane = tid & 63, wid = tid >> 6;
    int wm = wid >> 1, wn = wid & 1;
    int lr = lane & 15, lq = lane >> 4;
    int cg = tid & 15;
    int iN = nt * SBN1;
    int arow_tok[8];
    for (int p2 = 0; p2 < 8; ++p2) {
        int r = (tid >> 4) + p2 * 16;
        int m = mtile * BM + r;
        arow_tok[p2] = (m < count) ? ((expert < NE) ? list[expert * T_TOK + m] : m) : -1;
    }
    f32x4 accg[4][2] = {};
    f32x4 accu[4][2] = {};
    for (int kt = 0; kt < H_DIM; kt += BK) {
        for (int p2 = 0; p2 < 8; ++p2) {
            int r = (tid >> 4) + p2 * 16;
            int tok = arow_tok[p2];
            float4 v = make_float4(0.f, 0.f, 0.f, 0.f);
            if (tok >= 0) v = *(const float4*)(x + (size_t)tok * H_DIM + kt + cg * 4);
            bf16* dst = &As[r][cg * 4];
            dst[0] = (bf16)v.x; dst[1] = (bf16)v.y; dst[2] = (bf16)v.z; dst[3] = (bf16)v.w;
        }
        for (int p2 = 0; p2 < 4; ++p2) {
            int r = (tid >> 4) + p2 * 16;
            float4 vg = *(const float4*)(wg + (size_t)(iN + r) * H_DIM + kt + cg * 4);
            float4 vu = *(const float4*)(wu + (size_t)(iN + r) * H_DIM + kt + cg * 4);
            bf16* dg = &Bg[r][cg * 4];
            dg[0] = (bf16)vg.x; dg[1] = (bf16)vg.y; dg[2] = (bf16)vg.z; dg[3] = (bf16)vg.w;
            bf16* du = &Bu[r][cg * 4];
            du[0] = (bf16)vu.x; du[1] = (bf16)vu.y; du[2] = (bf16)vu.z; du[3] = (bf16)vu.w;
        }
        __syncthreads();
        for (int kk = 0; kk < BK; kk += 32) {
            bf16x8 af[4], bgf[2], buf2[2];
            for (int mi = 0; mi < 4; ++mi)
                af[mi] = *(const bf16x8*)&As[wm * 64 + mi * 16 + lr][kk + lq * 8];
            for (int ni = 0; ni < 2; ++ni) {
                bgf[ni] = *(const bf16x8*)&Bg[wn * 32 + ni * 16 + lr][kk + lq * 8];
                buf2[ni] = *(const bf16x8*)&Bu[wn * 32 + ni * 16 + lr][kk + lq * 8];
            }
            for (int mi = 0; mi < 4; ++mi)
                for (int ni = 0; ni < 2; ++ni) {
                    accg[mi][ni] = __builtin_amdgcn_mfma_f32_16x16x32_bf16(af[mi], bgf[ni], accg[mi][ni], 0, 0, 0);
                    accu[mi][ni] = __builtin_amdgcn_mfma_f32_16x16x32_bf16(af[mi], buf2[ni], accu[mi][ni], 0, 0, 0);
                }
        }
        __syncthreads();
    }
    for (int mi = 0; mi < 4; ++mi)
        for (int ni = 0; ni < 2; ++ni)
            for (int r2 = 0; r2 < 4; ++r2) {
                int row = wm * 64 + mi * 16 + lq * 4 + r2;
                int m = mtile * BM + row;
                if (m >= count) continue;
                float g = accg[mi][ni][r2], u = accu[mi][ni][r2];
                float hv = g / (1.f + expf(-g)) * u;
                int col = iN + wn * 32 + ni * 16 + lr;
                h[(size_t)(rowbase + m) * I_DIM + col] = (bf16)hv;
            }
}

__global__ __launch_bounds__(256) void ffn2_slow(
    const bf16* __restrict__ h, const float* __restrict__ w_down,
    const float* __restrict__ wsd, const int* __restrict__ cnt,
    const int* __restrict__ offs, const int* __restrict__ list,
    const float* __restrict__ comb, float* __restrict__ out) {
    int nt = blockIdx.x % SNT2;
    int mt = blockIdx.x / SNT2;
    int expert, mtile, count;
    if (!map_tile(cnt, mt, BM, expert, mtile, count)) return;
    int rowbase = offs[expert];
    const float* wd = (expert < NE) ? (w_down + (size_t)expert * N_S) : wsd;
    __shared__ bf16 As[BM][BK + 8];
    __shared__ bf16 Bs[SBN2][BK + 8];
    int tid = threadIdx.x;
    int lane = tid & 63, wid = tid >> 6;
    int wm = wid >> 1, wn = wid & 1;
    int lr = lane & 15, lq = lane >> 4;
    int hN = nt * SBN2;
    int arow_m[4];
    for (int p2 = 0; p2 < 4; ++p2) {
        int r = (tid >> 3) + p2 * 32;
        int m = mtile * BM + r;
        arow_m[p2] = (m < count) ? m : -1;
    }
    f32x4 acc[4][2] = {};
    for (int kt = 0; kt < I_DIM; kt += BK) {
        for (int p2 = 0; p2 < 4; ++p2) {
            int r = (tid >> 3) + p2 * 32;
            int m = arow_m[p2];
            float4 v = make_float4(0.f, 0.f, 0.f, 0.f);
            if (m >= 0) v = *(const float4*)(h + (size_t)(rowbase + m) * I_DIM + kt + (tid & 7) * 8);
            *(float4*)&As[r][(tid & 7) * 8] = v;
        }
        for (int p2 = 0; p2 < 4; ++p2) {
            int r = (tid >> 4) + p2 * 16;
            float4 v = *(const float4*)(wd + (size_t)(hN + r) * I_DIM + kt + (tid & 15) * 4);
            bf16* d = &Bs[r][(tid & 15) * 4];
            d[0] = (bf16)v.x; d[1] = (bf16)v.y; d[2] = (bf16)v.z; d[3] = (bf16)v.w;
        }
        __syncthreads();
        for (int kk = 0; kk < BK; kk += 32) {
            bf16x8 af[4], bf2[2];
            for (int mi = 0; mi < 4; ++mi)
                af[mi] = *(const bf16x8*)&As[wm * 64 + mi * 16 + lr][kk + lq * 8];
            for (int ni = 0; ni < 2; ++ni)
                bf2[ni] = *(const bf16x8*)&Bs[wn * 32 + ni * 16 + lr][kk + lq * 8];
            for (int mi = 0; mi < 4; ++mi)
                for (int ni = 0; ni < 2; ++ni)
                    acc[mi][ni] = __builtin_amdgcn_mfma_f32_16x16x32_bf16(af[mi], bf2[ni], acc[mi][ni], 0, 0, 0);
        }
        __syncthreads();
    }
    for (int mi = 0; mi < 4; ++mi)
        for (int ni = 0; ni < 2; ++ni)
            for (int r2 = 0; r2 < 4; ++r2) {
                int row = wm * 64 + mi * 16 + lq * 4 + r2;
                int m = mtile * BM + row;
                if (m >= count) continue;
                int tok; float wgt;
                if (expert < NE) {
                    tok = list[expert * T_TOK + m];
                    wgt = comb[tok * NE + expert];
                } else {
                    tok = m;
                    wgt = 1.f;
                }
                int col = hN + wn * 32 + ni * 16 + lr;
                atomicAdd(&out[(size_t)tok * H_DIM + col], wgt * acc[mi][ni][r2]);
            }
}

extern "C" void kernel_launch(void* const* d_in, const int* in_sizes, int n_in,
                              void* d_out, int out_size, void* d_ws, size_t ws_size,
                              hipStream_t stream) {
    (void)in_sizes; (void)n_in; (void)out_size;
    const float* x      = (const float*)d_in[0];
    const float* gate_w = (const float*)d_in[1];
    const float* w_gate = (const float*)d_in[2];
    const float* w_up   = (const float*)d_in[3];
    const float* w_down = (const float*)d_in[4];
    const float* wsg    = (const float*)d_in[5];
    const float* wsu    = (const float*)d_in[6];
    const float* wsd    = (const float*)d_in[7];
    float* out = (float*)d_out;
    char* ws = (char*)d_ws;
    int*    cnt    = (int*)(ws + WS_CNT);
    int*    offs   = (int*)(ws + WS_OFFS);
    float*  comb   = (float*)(ws + WS_COMB);
    int4*   tok_ep = (int4*)(ws + WS_TOKEP);
    float2* tok_w  = (float2*)(ws + WS_TOKW);
    int*    list   = (int*)(ws + WS_LIST);
    bf16*   xb     = (bf16*)(ws + WS_XB);

    hipMemsetAsync(cnt, 0, 64, stream);
    gate_kernel<<<T_TOK, 64, 0, stream>>>(x, gate_w, comb, tok_ep, tok_w, cnt, list, xb);
    offs_kernel<<<1, 64, 0, stream>>>(cnt, offs);

    if (ws_size >= WS_NEED) {
        bf16* wgb  = (bf16*)(ws + WS_WGB);
        bf16* wub  = (bf16*)(ws + WS_WUB);
        bf16* wdb  = (bf16*)(ws + WS_WDB);
        bf16* wsgb = (bf16*)(ws + WS_WSGB);
        bf16* wsub = (bf16*)(ws + WS_WSUB);
        bf16* wsdb = (bf16*)(ws + WS_WSDB);
        bf16* h    = (bf16*)(ws + WS_HF);
        bf16* eo   = (bf16*)(ws + WS_EO);    // aliases wgb (dead after ffn1)
        size_t total8 = (2 * N_W + 2 * N_S) / 8;     // wg, wu, wsg, wsu
        int cblocks = (int)((total8 + 255) / 256);   // 24768
        convert_kernel<<<cblocks, 256, 0, stream>>>(w_gate, w_up, wsg, wsu,
                                                    wgb, wub, wsgb, wsub);
        ffn1_fast<<<CONV1_BLKS + MT_MAX * NT1, 256, 0, stream>>>(
            xb, wgb, wub, wsgb, wsub, cnt, offs, list, h,
            w_down, wsd, wdb, wsdb);
        ffn2_fast<<<MT_MAX * NT2, 256, 0, stream>>>(h, wdb, wsdb, cnt, offs, eo);
        combine_kernel<<<T_TOK, 256, 0, stream>>>(eo, offs, tok_ep, tok_w, out);
    } else {
        bf16* h = (bf16*)(ws + WS_HS);
        hipMemsetAsync(out, 0, (size_t)T_TOK * H_DIM * sizeof(float), stream);
        ffn1_slow<<<MT_MAX * SNT1, 256, 0, stream>>>(x, w_gate, w_up, wsg, wsu, cnt, offs, list, h);
        ffn2_slow<<<MT_MAX * SNT2, 256, 0, stream>>>(h, w_down, wsd, cnt, offs, list, comb, out);
    }
}

// Round 3
// 766.619 us; speedup vs baseline: 1.0200x; 1.0200x over previous
//
#include <hip/hip_runtime.h>
#include <hip/hip_bf16.h>

#define H_DIM 1024
#define I_DIM 2752   // = 43 * 64
#define T_TOK 4096
#define NE 8
#define NROWS (3 * T_TOK)   // 8192 routed pairs + 4096 shared

typedef __bf16 bf16;
typedef __bf16 bf16x8 __attribute__((ext_vector_type(8)));
typedef __bf16 bf16x4 __attribute__((ext_vector_type(4)));
typedef float f32x4 __attribute__((ext_vector_type(4)));

// ---- sizes (elements) ----
constexpr size_t N_X = (size_t)T_TOK * H_DIM;        // 4,194,304
constexpr size_t N_W = (size_t)NE * I_DIM * H_DIM;   // 22,544,384
constexpr size_t N_S = (size_t)I_DIM * H_DIM;        // 2,818,048
constexpr size_t N_H = (size_t)NROWS * I_DIM;        // 33,816,576

// ---- workspace layout (bytes) ----
constexpr size_t WS_CNT  = 0;
constexpr size_t WS_OFFS = 64;
constexpr size_t WS_COMB = 256;                                  // T*NE fp32 (slow path only)
constexpr size_t WS_TOKEP = WS_COMB + (size_t)T_TOK * NE * 4;    // int4 per token
constexpr size_t WS_TOKW  = WS_TOKEP + (size_t)T_TOK * 16;       // float2 per token
constexpr size_t WS_LIST  = WS_TOKW + (size_t)T_TOK * 8;
constexpr size_t WS_XB   = WS_LIST + (size_t)NE * T_TOK * 4;
constexpr size_t WS_WGB  = WS_XB  + N_X * 2;
constexpr size_t WS_WUB  = WS_WGB + N_W * 2;
constexpr size_t WS_WDB  = WS_WUB + N_W * 2;
constexpr size_t WS_WSGB = WS_WDB + N_W * 2;
constexpr size_t WS_WSUB = WS_WSGB + N_S * 2;
constexpr size_t WS_WSDB = WS_WSUB + N_S * 2;
constexpr size_t WS_HF   = WS_WSDB + N_S * 2;
constexpr size_t WS_NEED = WS_HF + N_H * 2;          // ~218 MB
// eo[NROWS][H_DIM] bf16 (24 MB) aliases wgb (45 MB) — wgb is dead after ffn1
constexpr size_t WS_EO   = WS_WGB;
// slow-path h (fallback if ws too small)
constexpr size_t WS_HS   = WS_XB;

// direct global->LDS, 16B per lane. LDS dst is wave-uniform base; HW scatters lane*16.
__device__ inline void gll16(const bf16* g, bf16* l) {
    __builtin_amdgcn_global_load_lds(
        (const __attribute__((address_space(1))) unsigned int*)g,
        (__attribute__((address_space(3))) unsigned int*)l, 16, 0, 0);
}

// counted-vmcnt wait (T4): stage(t) landed; stage(t+1)'s 4 loads stay in flight.
#define VM_WAIT4 asm volatile("s_waitcnt vmcnt(4)" ::: "memory")
#define VM_DRAIN asm volatile("s_waitcnt vmcnt(0)" ::: "memory")

// ---------------- gating (coalesced; fuses x -> bf16 conversion) ----------------
__global__ void gate_kernel(const float* __restrict__ x, const float* __restrict__ gw,
                            float* __restrict__ comb, int4* __restrict__ tok_ep,
                            float2* __restrict__ tok_w, int* __restrict__ cnt,
                            int* __restrict__ list, bf16* __restrict__ xb) {
    int t = blockIdx.x;
    int lane = threadIdx.x;   // 64
    const float* xr = x + (size_t)t * H_DIM;
    float4 xv[4];
    for (int j = 0; j < 4; ++j) xv[j] = *(const float4*)(xr + lane * 4 + j * 256);
    float p[NE] = {};
    for (int e = 0; e < NE; ++e) {
        const float* wr = gw + (size_t)e * H_DIM;
        for (int j = 0; j < 4; ++j) {
            float4 wv = *(const float4*)(wr + lane * 4 + j * 256);
            p[e] += xv[j].x * wv.x + xv[j].y * wv.y + xv[j].z * wv.z + xv[j].w * wv.w;
        }
    }
    for (int j = 0; j < 4; ++j) {
        bf16x4 b = { (bf16)xv[j].x, (bf16)xv[j].y, (bf16)xv[j].z, (bf16)xv[j].w };
        *(bf16x4*)(xb + (size_t)t * H_DIM + lane * 4 + j * 256) = b;
    }
    for (int o = 32; o >= 1; o >>= 1)
        for (int e = 0; e < NE; ++e) p[e] += __shfl_xor(p[e], o);
    if (lane == 0) {
        float m = p[0];
        for (int j = 1; j < NE; ++j) m = fmaxf(m, p[j]);
        float s[NE], Z = 0.f;
        for (int j = 0; j < NE; ++j) { s[j] = expf(p[j] - m); Z += s[j]; }
        for (int j = 0; j < NE; ++j) s[j] /= Z;
        int i0 = 0;
        for (int j = 1; j < NE; ++j) if (s[j] > s[i0]) i0 = j;
        int i1 = (i0 == 0) ? 1 : 0;
        for (int j = 0; j < NE; ++j) if (j != i0 && s[j] > s[i1]) i1 = j;
        float d = s[i0] + s[i1] + 1e-20f;
        float w0 = s[i0] / d, w1 = s[i1] / d;
        for (int j = 0; j < NE; ++j) comb[t * NE + j] = 0.f;
        comb[t * NE + i0] = w0;
        comb[t * NE + i1] = w1;
        int p0 = atomicAdd(&cnt[i0], 1); list[i0 * T_TOK + p0] = t;
        int p1 = atomicAdd(&cnt[i1], 1); list[i1 * T_TOK + p1] = t;
        tok_ep[t] = make_int4(i0, p0, i1, p1);
        tok_w[t] = make_float2(w0, w1);
    }
}

__global__ void offs_kernel(const int* __restrict__ cnt, int* __restrict__ offs) {
    if (threadIdx.x == 0) {
        int a = 0;
        for (int e = 0; e < NE; ++e) { offs[e] = a; a += cnt[e]; }
        offs[NE] = a;   // routed total; shared rows start here
    }
}

// ---------------- fp32 -> bf16 conversion ----------------
__device__ inline void cvt8(const float* __restrict__ s, bf16* __restrict__ d) {
    float4 a = ((const float4*)s)[0];
    float4 b = ((const float4*)s)[1];
    bf16x8 v = { (bf16)a.x, (bf16)a.y, (bf16)a.z, (bf16)a.w,
                 (bf16)b.x, (bf16)b.y, (bf16)b.z, (bf16)b.w };
    *(bf16x8*)d = v;
}

// converts ffn1's weights only (w_down converted inside ffn1's role blocks)
__global__ void convert_kernel(const float* __restrict__ wg, const float* __restrict__ wu,
                               const float* __restrict__ wsg, const float* __restrict__ wsu,
                               bf16* wgb, bf16* wub, bf16* wsgb, bf16* wsub) {
    size_t i = ((size_t)blockIdx.x * 256 + threadIdx.x) * 8;
    if (i < N_W) { cvt8(wg + i, wgb + i); return; }
    i -= N_W;
    if (i < N_W) { cvt8(wu + i, wub + i); return; }
    i -= N_W;
    if (i < N_S) { cvt8(wsg + i, wsgb + i); return; }
    i -= N_S;
    if (i < N_S) { cvt8(wsu + i, wsub + i); }
}

#define BM 128
#define MT_MAX 104
#define BK 64
#define BK2 32
#define NH1 (H_DIM / BK2)   // 32 half-steps
#define NH2 (I_DIM / BK2)   // 86 half-steps

// supertile map: expert-major; within expert, groups of 8 m-tiles x nt_cnt n-tiles,
// msub fastest (8 consecutive work items share a B n-tile; a group of 8*nt_cnt items
// touches only an 8-m-tile A-slab + nt_cnt B-tiles).
__device__ inline bool map_super(const int* cnt, int bx, int nt_cnt,
                                 int& expert, int& mtile, int& nt, int& count) {
    for (int e = 0; e <= NE; ++e) {
        int c = (e < NE) ? cnt[e] : T_TOK;
        int tiles = (c + BM - 1) / BM;
        int blocks = tiles * nt_cnt;
        if (bx < blocks) {
            int full = tiles & ~7;              // m-tiles in full groups of 8
            int fullblocks = full * nt_cnt;
            int mg0, gsz, rem;
            if (bx < fullblocks) { mg0 = (bx / (nt_cnt * 8)) * 8; gsz = 8; rem = bx % (nt_cnt * 8); }
            else                 { mg0 = full; gsz = tiles - full; rem = bx - fullblocks; }
            nt = rem / gsz;
            mtile = mg0 + rem % gsz;
            expert = e; count = c;
            return true;
        }
        bx -= blocks;
    }
    return false;
}

// total active GEMM blocks (must match map_super's walk)
__device__ inline int active_blocks(const int* cnt, int nt_cnt) {
    int t = 0;
    for (int e = 0; e < NE; ++e) t += (cnt[e] + BM - 1) / BM;
    return (t + T_TOK / BM) * nt_cnt;
}

// bijective XCD-chunked swizzle (m204 variant): block with hw XCD = bx%8 gets a
// CONTIGUOUS chunk of the supertile sequence, so msub-neighbors sharing a B-tile
// land on the SAME XCD's L2.
__device__ inline int xcd_chunk(int bx, int n) {
    int q = n >> 3, r = n & 7;
    int x = bx & 7, o = bx >> 3;
    return (x < r ? x * (q + 1) : r * (q + 1) + (x - r) * q) + o;
}

// linear map (slow path)
__device__ inline bool map_tile(const int* cnt, int mt, int bm,
                                int& expert, int& mtile, int& count) {
    for (int e = 0; e <= NE; ++e) {
        int c = (e < NE) ? cnt[e] : T_TOK;
        int tiles = (c + bm - 1) / bm;
        if (mt < tiles) { expert = e; mtile = mt; count = c; return true; }
        mt -= tiles;
    }
    return false;
}

// ---------------- fast GEMM1: h = silu(x@Wg^T) * (x@Wu^T) ----------------
// 2-buffer (32KB, occupancy-preserving) pipeline at BK2=32 granularity with
// COUNTED vmcnt: issue stage(t+1), vmcnt(4) waits only stage(t); stage(t+1)'s
// 4 loads stay in flight across both barriers (T4). No drain-to-0 in the loop.
// Swizzle: LDS[r][g16] holds global 16B-group g16 ^ ((r>>1)&3) (involution,
// pre-applied on the per-lane global source address for global_load_lds).
#define BN1 64
#define NT1 (I_DIM / BN1)   // 43
#define CONV1_BLKS 3096     // (N_W + N_S) / (256*32) exactly; multiple of 8

__global__ __launch_bounds__(256) void ffn1_fast(
    const bf16* __restrict__ xb, const bf16* __restrict__ wgb,
    const bf16* __restrict__ wub, const bf16* __restrict__ wsgb,
    const bf16* __restrict__ wsub, const int* __restrict__ cnt,
    const int* __restrict__ offs, const int* __restrict__ list,
    bf16* __restrict__ h,
    const float* __restrict__ wd_f, const float* __restrict__ wsd_f,
    bf16* __restrict__ wdb, bf16* __restrict__ wsdb) {
    if (blockIdx.x < CONV1_BLKS) {
        size_t base = (size_t)blockIdx.x * 8192 + (size_t)threadIdx.x * 8;
        for (int j = 0; j < 4; ++j) {
            size_t i = base + (size_t)j * 2048;
            if (i < N_W) cvt8(wd_f + i, wdb + i);
            else         cvt8(wsd_f + (i - N_W), wsdb + (i - N_W));
        }
        return;
    }
    int bx = blockIdx.x - CONV1_BLKS;   // CONV1_BLKS % 8 == 0, so bx%8 == hw XCD
    int nact = active_blocks(cnt, NT1);
    if (bx >= nact) return;
    bx = xcd_chunk(bx, nact);
    int expert, mtile, nt, count;
    if (!map_super(cnt, bx, NT1, expert, mtile, nt, count)) return;
    int rowbase = offs[expert];
    const bf16* wg = (expert < NE) ? (wgb + (size_t)expert * N_S) : wsgb;
    const bf16* wu = (expert < NE) ? (wub + (size_t)expert * N_S) : wsub;

    __shared__ bf16 As[2][BM][BK2];    // 16 KB
    __shared__ bf16 Bg[2][BN1][BK2];   // 8 KB
    __shared__ bf16 Bu[2][BN1][BK2];   // 8 KB

    int tid = threadIdx.x;
    int lane = tid & 63, wid = tid >> 6;
    int wm = wid >> 1, wn = wid & 1;
    int lr = lane & 15, lq = lane >> 4;
    int l4 = lane >> 2, c4 = lane & 3;
    int c4s = c4 ^ ((lane >> 3) & 3);   // pre-swizzled source 16B-group
    int iN = nt * BN1;

    const bf16* aptr0;
    const bf16* aptr1;
    {
        int r0 = wid * 32 + l4;
        int m0 = mtile * BM + r0;
        int t0 = 0;
        if (m0 < count) t0 = (expert < NE) ? list[expert * T_TOK + m0] : m0;
        aptr0 = xb + (size_t)t0 * H_DIM + c4s * 8;
        int r1 = wid * 32 + 16 + l4;
        int m1 = mtile * BM + r1;
        int t1 = 0;
        if (m1 < count) t1 = (expert < NE) ? list[expert * T_TOK + m1] : m1;
        aptr1 = xb + (size_t)t1 * H_DIM + c4s * 8;
    }
    int rb = wid * 16 + l4;
    const bf16* gp = wg + (size_t)(iN + rb) * H_DIM + c4s * 8;
    const bf16* up = wu + (size_t)(iN + rb) * H_DIM + c4s * 8;

    int fragoff = (lq ^ ((lr >> 1) & 3)) << 3;
    int arow[4], brow[2];
    for (int mi = 0; mi < 4; ++mi) arow[mi] = (wm * 64 + mi * 16 + lr) * BK2 + fragoff;
    for (int ni = 0; ni < 2; ++ni) brow[ni] = (wn * 32 + ni * 16 + lr) * BK2 + fragoff;

    f32x4 accg[4][2] = {};
    f32x4 accu[4][2] = {};

    auto stage = [&](int p, int hs) {   // 4 gll16 per thread
        int off = hs * BK2;
        gll16(aptr0 + off, &As[p][wid * 32][0]);
        gll16(aptr1 + off, &As[p][wid * 32 + 16][0]);
        gll16(gp + off, &Bg[p][wid * 16][0]);
        gll16(up + off, &Bu[p][wid * 16][0]);
    };

    stage(0, 0);
    int p = 0;
    for (int hs = 0; hs < NH1; ++hs) {
        int hs1 = (hs + 1 < NH1) ? hs + 1 : NH1 - 1;   // clamp keeps counts uniform
        stage(p ^ 1, hs1);
        VM_WAIT4;                        // stage(hs) landed; stage(hs+1) in flight
        __builtin_amdgcn_s_barrier();    // all waves' stage(hs) landed
        __builtin_amdgcn_sched_barrier(0);
        const bf16* Ap  = &As[p][0][0];
        const bf16* Bgp = &Bg[p][0][0];
        const bf16* Bup = &Bu[p][0][0];
        bf16x8 af[4], bgf[2], buf_[2];
        for (int mi = 0; mi < 4; ++mi) af[mi] = *(const bf16x8*)(Ap + arow[mi]);
        for (int ni = 0; ni < 2; ++ni) {
            bgf[ni]  = *(const bf16x8*)(Bgp + brow[ni]);
            buf_[ni] = *(const bf16x8*)(Bup + brow[ni]);
        }
        for (int mi = 0; mi < 4; ++mi)
            for (int ni = 0; ni < 2; ++ni) {
                accg[mi][ni] = __builtin_amdgcn_mfma_f32_16x16x32_bf16(af[mi], bgf[ni], accg[mi][ni], 0, 0, 0);
                accu[mi][ni] = __builtin_amdgcn_mfma_f32_16x16x32_bf16(af[mi], buf_[ni], accu[mi][ni], 0, 0, 0);
            }
        __builtin_amdgcn_s_barrier();    // readers done; buf p reusable next iter
        p ^= 1;
    }
    VM_DRAIN;   // pending LDS writes must not outlive the workgroup
    for (int mi = 0; mi < 4; ++mi)
        for (int ni = 0; ni < 2; ++ni)
            for (int r2 = 0; r2 < 4; ++r2) {
                int row = wm * 64 + mi * 16 + lq * 4 + r2;
                int m = mtile * BM + row;
                if (m >= count) continue;
                float g = accg[mi][ni][r2], u = accu[mi][ni][r2];
                float hv = g / (1.f + expf(-g)) * u;
                int col = iN + wn * 32 + ni * 16 + lr;
                h[(size_t)(rowbase + m) * I_DIM + col] = (bf16)hv;
            }
}

// ---------------- fast GEMM2: eo = h @ Wd^T, 128x128 tiles, counted-vmcnt 2-buf ----------------
#define BN2 128
#define NT2 (H_DIM / BN2)   // 8

__global__ __launch_bounds__(256) void ffn2_fast(
    const bf16* __restrict__ h, const bf16* __restrict__ wdb,
    const bf16* __restrict__ wsdb, const int* __restrict__ cnt,
    const int* __restrict__ offs, bf16* __restrict__ eo) {
    int nact = active_blocks(cnt, NT2);
    int bx = blockIdx.x;
    if (bx >= nact) return;
    bx = xcd_chunk(bx, nact);
    int expert, mtile, nt, count;
    if (!map_super(cnt, bx, NT2, expert, mtile, nt, count)) return;
    int rowbase = offs[expert];
    const bf16* wd = (expert < NE) ? (wdb + (size_t)expert * N_S) : wsdb;

    __shared__ bf16 As[2][BM][BK2];    // 16 KB
    __shared__ bf16 Bs[2][BN2][BK2];   // 16 KB

    int tid = threadIdx.x;
    int lane = tid & 63, wid = tid >> 6;
    int wm = wid >> 1, wn = wid & 1;
    int lr = lane & 15, lq = lane >> 4;
    int l4 = lane >> 2, c4 = lane & 3;
    int c4s = c4 ^ ((lane >> 3) & 3);
    int hN = nt * BN2;

    const bf16* aptr0;
    const bf16* aptr1;
    {
        int r0 = wid * 32 + l4;
        int m0 = mtile * BM + r0;
        size_t h0 = (size_t)rowbase + ((m0 < count) ? m0 : 0);
        aptr0 = h + h0 * I_DIM + c4s * 8;
        int r1 = wid * 32 + 16 + l4;
        int m1 = mtile * BM + r1;
        size_t h1 = (size_t)rowbase + ((m1 < count) ? m1 : 0);
        aptr1 = h + h1 * I_DIM + c4s * 8;
    }
    const bf16* bptr0;
    const bf16* bptr1;
    {
        int r0 = wid * 32 + l4;
        bptr0 = wd + (size_t)(hN + r0) * I_DIM + c4s * 8;
        int r1 = wid * 32 + 16 + l4;
        bptr1 = wd + (size_t)(hN + r1) * I_DIM + c4s * 8;
    }

    int fragoff = (lq ^ ((lr >> 1) & 3)) << 3;
    int arow[4], brow[4];
    for (int mi = 0; mi < 4; ++mi) arow[mi] = (wm * 64 + mi * 16 + lr) * BK2 + fragoff;
    for (int ni = 0; ni < 4; ++ni) brow[ni] = (wn * 64 + ni * 16 + lr) * BK2 + fragoff;

    f32x4 acc[4][4] = {};

    auto stage = [&](int p, int hs) {   // 4 gll16 per thread
        int off = hs * BK2;
        gll16(aptr0 + off, &As[p][wid * 32][0]);
        gll16(aptr1 + off, &As[p][wid * 32 + 16][0]);
        gll16(bptr0 + off, &Bs[p][wid * 32][0]);
        gll16(bptr1 + off, &Bs[p][wid * 32 + 16][0]);
    };

    stage(0, 0);
    int p = 0;
    for (int hs = 0; hs < NH2; ++hs) {
        int hs1 = (hs + 1 < NH2) ? hs + 1 : NH2 - 1;
        stage(p ^ 1, hs1);
        VM_WAIT4;
        __builtin_amdgcn_s_barrier();
        __builtin_amdgcn_sched_barrier(0);
        const bf16* Ap = &As[p][0][0];
        const bf16* Bp = &Bs[p][0][0];
        bf16x8 af[4], bf2[4];
        for (int mi = 0; mi < 4; ++mi) af[mi] = *(const bf16x8*)(Ap + arow[mi]);
        for (int ni = 0; ni < 4; ++ni) bf2[ni] = *(const bf16x8*)(Bp + brow[ni]);
        for (int mi = 0; mi < 4; ++mi)
            for (int ni = 0; ni < 4; ++ni)
                acc[mi][ni] = __builtin_amdgcn_mfma_f32_16x16x32_bf16(af[mi], bf2[ni], acc[mi][ni], 0, 0, 0);
        __builtin_amdgcn_s_barrier();
        p ^= 1;
    }
    VM_DRAIN;
    for (int mi = 0; mi < 4; ++mi)
        for (int ni = 0; ni < 4; ++ni)
            for (int r2 = 0; r2 < 4; ++r2) {
                int row = wm * 64 + mi * 16 + lq * 4 + r2;
                int m = mtile * BM + row;
                if (m >= count) continue;
                int col = hN + wn * 64 + ni * 16 + lr;
                eo[(size_t)(rowbase + m) * H_DIM + col] = (bf16)acc[mi][ni][r2];
            }
}

// ---------------- combine: out[t] = w0*eo[r0] + w1*eo[r1] + eo[shared_t] ----------------
__global__ __launch_bounds__(256) void combine_kernel(
    const bf16* __restrict__ eo, const int* __restrict__ offs,
    const int4* __restrict__ tok_ep, const float2* __restrict__ tok_w,
    float* __restrict__ out) {
    int t = blockIdx.x;
    int c = threadIdx.x * 4;
    int4 ep = tok_ep[t];
    float2 w = tok_w[t];
    size_t r0 = (size_t)(offs[ep.x] + ep.y) * H_DIM + c;
    size_t r1 = (size_t)(offs[ep.z] + ep.w) * H_DIM + c;
    size_t rs = (size_t)(offs[NE] + t) * H_DIM + c;
    bf16x4 a = *(const bf16x4*)(eo + r0);
    bf16x4 b = *(const bf16x4*)(eo + r1);
    bf16x4 s = *(const bf16x4*)(eo + rs);
    float4 o;
    o.x = w.x * (float)a[0] + w.y * (float)b[0] + (float)s[0];
    o.y = w.x * (float)a[1] + w.y * (float)b[1] + (float)s[1];
    o.z = w.x * (float)a[2] + w.y * (float)b[2] + (float)s[2];
    o.w = w.x * (float)a[3] + w.y * (float)b[3] + (float)s[3];
    *(float4*)(out + (size_t)t * H_DIM + c) = o;
}

// ================= slow fallback (fp32 staging, atomics) =================
#define SBN1 64
#define SNT1 (I_DIM / SBN1)
#define SBN2 64
#define SNT2 (H_DIM / SBN2)

__global__ __launch_bounds__(256) void ffn1_slow(
    const float* __restrict__ x, const float* __restrict__ w_gate,
    const float* __restrict__ w_up, const float* __restrict__ wsg,
    const float* __restrict__ wsu, const int* __restrict__ cnt,
    const int* __restrict__ offs, const int* __restrict__ list,
    bf16* __restrict__ h) {
    int nt = blockIdx.x % SNT1;
    int mt = blockIdx.x / SNT1;
    int expert, mtile, count;
    if (!map_tile(cnt, mt, BM, expert, mtile, count)) return;
    int rowbase = offs[expert];
    const float* wg = (expert < NE) ? (w_gate + (size_t)expert * N_S) : wsg;
    const float* wu = (expert < NE) ? (w_up + (size_t)expert * N_S) : wsu;
    __shared__ bf16 As[BM][BK + 8];
    __shared__ bf16 Bg[SBN1][BK + 8];
    __shared__ bf16 Bu[SBN1][BK + 8];
    int tid = threadIdx.x;
    int lane = tid & 63, wid = tid >> 6;
    int wm = wid >> 1, wn = wid & 1;
    int lr = lane & 15, lq = lane >> 4;
    int cg = tid & 15;
    int iN = nt * SBN1;
    int arow_tok[8];
    for (int p2 = 0; p2 < 8; ++p2) {
        int r = (tid >> 4) + p2 * 16;
        int m = mtile * BM + r;
        arow_tok[p2] = (m < count) ? ((expert < NE) ? list[expert * T_TOK + m] : m) : -1;
    }
    f32x4 accg[4][2] = {};
    f32x4 accu[4][2] = {};
    for (int kt = 0; kt < H_DIM; kt += BK) {
        for (int p2 = 0; p2 < 8; ++p2) {
            int r = (tid >> 4) + p2 * 16;
            int tok = arow_tok[p2];
            float4 v = make_float4(0.f, 0.f, 0.f, 0.f);
            if (tok >= 0) v = *(const float4*)(x + (size_t)tok * H_DIM + kt + cg * 4);
            bf16* dst = &As[r][cg * 4];
            dst[0] = (bf16)v.x; dst[1] = (bf16)v.y; dst[2] = (bf16)v.z; dst[3] = (bf16)v.w;
        }
        for (int p2 = 0; p2 < 4; ++p2) {
            int r = (tid >> 4) + p2 * 16;
            float4 vg = *(const float4*)(wg + (size_t)(iN + r) * H_DIM + kt + cg * 4);
            float4 vu = *(const float4*)(wu + (size_t)(iN + r) * H_DIM + kt + cg * 4);
            bf16* dg = &Bg[r][cg * 4];
            dg[0] = (bf16)vg.x; dg[1] = (bf16)vg.y; dg[2] = (bf16)vg.z; dg[3] = (bf16)vg.w;
            bf16* du = &Bu[r][cg * 4];
            du[0] = (bf16)vu.x; du[1] = (bf16)vu.y; du[2] = (bf16)vu.z; du[3] = (bf16)vu.w;
        }
        __syncthreads();
        for (int kk = 0; kk < BK; kk += 32) {
            bf16x8 af[4], bgf[2], buf2[2];
            for (int mi = 0; mi < 4; ++mi)
                af[mi] = *(const bf16x8*)&As[wm * 64 + mi * 16 + lr][kk + lq * 8];
            for (int ni = 0; ni < 2; ++ni) {
                bgf[ni] = *(const bf16x8*)&Bg[wn * 32 + ni * 16 + lr][kk + lq * 8];
                buf2[ni] = *(const bf16x8*)&Bu[wn * 32 + ni * 16 + lr][kk + lq * 8];
            }
            for (int mi = 0; mi < 4; ++mi)
                for (int ni = 0; ni < 2; ++ni) {
                    accg[mi][ni] = __builtin_amdgcn_mfma_f32_16x16x32_bf16(af[mi], bgf[ni], accg[mi][ni], 0, 0, 0);
                    accu[mi][ni] = __builtin_amdgcn_mfma_f32_16x16x32_bf16(af[mi], buf2[ni], accu[mi][ni], 0, 0, 0);
                }
        }
        __syncthreads();
    }
    for (int mi = 0; mi < 4; ++mi)
        for (int ni = 0; ni < 2; ++ni)
            for (int r2 = 0; r2 < 4; ++r2) {
                int row = wm * 64 + mi * 16 + lq * 4 + r2;
                int m = mtile * BM + row;
                if (m >= count) continue;
                float g = accg[mi][ni][r2], u = accu[mi][ni][r2];
                float hv = g / (1.f + expf(-g)) * u;
                int col = iN + wn * 32 + ni * 16 + lr;
                h[(size_t)(rowbase + m) * I_DIM + col] = (bf16)hv;
            }
}

__global__ __launch_bounds__(256) void ffn2_slow(
    const bf16* __restrict__ h, const float* __restrict__ w_down,
    const float* __restrict__ wsd, const int* __restrict__ cnt,
    const int* __restrict__ offs, const int* __restrict__ list,
    const float* __restrict__ comb, float* __restrict__ out) {
    int nt = blockIdx.x % SNT2;
    int mt = blockIdx.x / SNT2;
    int expert, mtile, count;
    if (!map_tile(cnt, mt, BM, expert, mtile, count)) return;
    int rowbase = offs[expert];
    const float* wd = (expert < NE) ? (w_down + (size_t)expert * N_S) : wsd;
    __shared__ bf16 As[BM][BK + 8];
    __shared__ bf16 Bs[SBN2][BK + 8];
    int tid = threadIdx.x;
    int lane = tid & 63, wid = tid >> 6;
    int wm = wid >> 1, wn = wid & 1;
    int lr = lane & 15, lq = lane >> 4;
    int hN = nt * SBN2;
    int arow_m[4];
    for (int p2 = 0; p2 < 4; ++p2) {
        int r = (tid >> 3) + p2 * 32;
        int m = mtile * BM + r;
        arow_m[p2] = (m < count) ? m : -1;
    }
    f32x4 acc[4][2] = {};
    for (int kt = 0; kt < I_DIM; kt += BK) {
        for (int p2 = 0; p2 < 4; ++p2) {
            int r = (tid >> 3) + p2 * 32;
            int m = arow_m[p2];
            float4 v = make_float4(0.f, 0.f, 0.f, 0.f);
            if (m >= 0) v = *(const float4*)(h + (size_t)(rowbase + m) * I_DIM + kt + (tid & 7) * 8);
            *(float4*)&As[r][(tid & 7) * 8] = v;
        }
        for (int p2 = 0; p2 < 4; ++p2) {
            int r = (tid >> 4) + p2 * 16;
            float4 v = *(const float4*)(wd + (size_t)(hN + r) * I_DIM + kt + (tid & 15) * 4);
            bf16* d = &Bs[r][(tid & 15) * 4];
            d[0] = (bf16)v.x; d[1] = (bf16)v.y; d[2] = (bf16)v.z; d[3] = (bf16)v.w;
        }
        __syncthreads();
        for (int kk = 0; kk < BK; kk += 32) {
            bf16x8 af[4], bf2[2];
            for (int mi = 0; mi < 4; ++mi)
                af[mi] = *(const bf16x8*)&As[wm * 64 + mi * 16 + lr][kk + lq * 8];
            for (int ni = 0; ni < 2; ++ni)
                bf2[ni] = *(const bf16x8*)&Bs[wn * 32 + ni * 16 + lr][kk + lq * 8];
            for (int mi = 0; mi < 4; ++mi)
                for (int ni = 0; ni < 2; ++ni)
                    acc[mi][ni] = __builtin_amdgcn_mfma_f32_16x16x32_bf16(af[mi], bf2[ni], acc[mi][ni], 0, 0, 0);
        }
        __syncthreads();
    }
    for (int mi = 0; mi < 4; ++mi)
        for (int ni = 0; ni < 2; ++ni)
            for (int r2 = 0; r2 < 4; ++r2) {
                int row = wm * 64 + mi * 16 + lq * 4 + r2;
                int m = mtile * BM + row;
                if (m >= count) continue;
                int tok; float wgt;
                if (expert < NE) {
                    tok = list[expert * T_TOK + m];
                    wgt = comb[tok * NE + expert];
                } else {
                    tok = m;
                    wgt = 1.f;
                }
                int col = hN + wn * 32 + ni * 16 + lr;
                atomicAdd(&out[(size_t)tok * H_DIM + col], wgt * acc[mi][ni][r2]);
            }
}

extern "C" void kernel_launch(void* const* d_in, const int* in_sizes, int n_in,
                              void* d_out, int out_size, void* d_ws, size_t ws_size,
                              hipStream_t stream) {
    (void)in_sizes; (void)n_in; (void)out_size;
    const float* x      = (const float*)d_in[0];
    const float* gate_w = (const float*)d_in[1];
    const float* w_gate = (const float*)d_in[2];
    const float* w_up   = (const float*)d_in[3];
    const float* w_down = (const float*)d_in[4];
    const float* wsg    = (const float*)d_in[5];
    const float* wsu    = (const float*)d_in[6];
    const float* wsd    = (const float*)d_in[7];
    float* out = (float*)d_out;
    char* ws = (char*)d_ws;
    int*    cnt    = (int*)(ws + WS_CNT);
    int*    offs   = (int*)(ws + WS_OFFS);
    float*  comb   = (float*)(ws + WS_COMB);
    int4*   tok_ep = (int4*)(ws + WS_TOKEP);
    float2* tok_w  = (float2*)(ws + WS_TOKW);
    int*    list   = (int*)(ws + WS_LIST);
    bf16*   xb     = (bf16*)(ws + WS_XB);

    hipMemsetAsync(cnt, 0, 64, stream);
    gate_kernel<<<T_TOK, 64, 0, stream>>>(x, gate_w, comb, tok_ep, tok_w, cnt, list, xb);
    offs_kernel<<<1, 64, 0, stream>>>(cnt, offs);

    if (ws_size >= WS_NEED) {
        bf16* wgb  = (bf16*)(ws + WS_WGB);
        bf16* wub  = (bf16*)(ws + WS_WUB);
        bf16* wdb  = (bf16*)(ws + WS_WDB);
        bf16* wsgb = (bf16*)(ws + WS_WSGB);
        bf16* wsub = (bf16*)(ws + WS_WSUB);
        bf16* wsdb = (bf16*)(ws + WS_WSDB);
        bf16* h    = (bf16*)(ws + WS_HF);
        bf16* eo   = (bf16*)(ws + WS_EO);    // aliases wgb (dead after ffn1)
        size_t total8 = (2 * N_W + 2 * N_S) / 8;     // wg, wu, wsg, wsu
        int cblocks = (int)((total8 + 255) / 256);   // 24768
        convert_kernel<<<cblocks, 256, 0, stream>>>(w_gate, w_up, wsg, wsu,
                                                    wgb, wub, wsgb, wsub);
        ffn1_fast<<<CONV1_BLKS + MT_MAX * NT1, 256, 0, stream>>>(
            xb, wgb, wub, wsgb, wsub, cnt, offs, list, h,
            w_down, wsd, wdb, wsdb);
        ffn2_fast<<<MT_MAX * NT2, 256, 0, stream>>>(h, wdb, wsdb, cnt, offs, eo);
        combine_kernel<<<T_TOK, 256, 0, stream>>>(eo, offs, tok_ep, tok_w, out);
    } else {
        bf16* h = (bf16*)(ws + WS_HS);
        hipMemsetAsync(out, 0, (size_t)T_TOK * H_DIM * sizeof(float), stream);
        ffn1_slow<<<MT_MAX * SNT1, 256, 0, stream>>>(x, w_gate, w_up, wsg, wsu, cnt, offs, list, h);
        ffn2_slow<<<MT_MAX * SNT2, 256, 0, stream>>>(h, w_down, wsd, cnt, offs, list, comb, out);
    }
}

// Round 4
// 733.005 us; speedup vs baseline: 1.0668x; 1.0459x over previous
//
#include <hip/hip_runtime.h>
#include <hip/hip_bf16.h>

#define H_DIM 1024
#define I_DIM 2752   // = 43 * 64
#define T_TOK 4096
#define NE 8
#define NROWS (3 * T_TOK)   // 8192 routed pairs + 4096 shared

typedef __bf16 bf16;
typedef __bf16 bf16x8 __attribute__((ext_vector_type(8)));
typedef __bf16 bf16x4 __attribute__((ext_vector_type(4)));
typedef float f32x4 __attribute__((ext_vector_type(4)));

// ---- sizes (elements) ----
constexpr size_t N_X = (size_t)T_TOK * H_DIM;        // 4,194,304
constexpr size_t N_W = (size_t)NE * I_DIM * H_DIM;   // 22,544,384
constexpr size_t N_S = (size_t)I_DIM * H_DIM;        // 2,818,048
constexpr size_t N_H = (size_t)NROWS * I_DIM;        // 33,816,576

// ---- workspace layout (bytes) ----
constexpr size_t WS_CNT  = 0;
constexpr size_t WS_OFFS = 64;
constexpr size_t WS_COMB = 256;                                  // T*NE fp32 (slow path only)
constexpr size_t WS_TOKEP = WS_COMB + (size_t)T_TOK * NE * 4;    // int4 per token
constexpr size_t WS_TOKW  = WS_TOKEP + (size_t)T_TOK * 16;       // float2 per token
constexpr size_t WS_LIST  = WS_TOKW + (size_t)T_TOK * 8;
constexpr size_t WS_XB   = WS_LIST + (size_t)NE * T_TOK * 4;
constexpr size_t WS_WGB  = WS_XB  + N_X * 2;
constexpr size_t WS_WUB  = WS_WGB + N_W * 2;
constexpr size_t WS_WDB  = WS_WUB + N_W * 2;
constexpr size_t WS_WSGB = WS_WDB + N_W * 2;
constexpr size_t WS_WSUB = WS_WSGB + N_S * 2;
constexpr size_t WS_WSDB = WS_WSUB + N_S * 2;
constexpr size_t WS_HF   = WS_WSDB + N_S * 2;
constexpr size_t WS_NEED = WS_HF + N_H * 2;          // ~218 MB
// eo[NROWS][H_DIM] bf16 (24 MB) aliases wgb (45 MB) — wgb is dead after ffn1
constexpr size_t WS_EO   = WS_WGB;
// slow-path h (fallback if ws too small)
constexpr size_t WS_HS   = WS_XB;

// direct global->LDS, 16B per lane. LDS dst is wave-uniform base; HW scatters lane*16.
__device__ inline void gll16(const bf16* g, bf16* l) {
    __builtin_amdgcn_global_load_lds(
        (const __attribute__((address_space(1))) unsigned int*)g,
        (__attribute__((address_space(3))) unsigned int*)l, 16, 0, 0);
}

// counted-vmcnt waits (T4): never drain to 0 in a main loop.
#define VM_WAIT4 asm volatile("s_waitcnt vmcnt(4)" ::: "memory")
#define VM_WAIT8 asm volatile("s_waitcnt vmcnt(8)" ::: "memory")
#define VM_DRAIN asm volatile("s_waitcnt vmcnt(0)" ::: "memory")

// ---------------- gating (coalesced; fuses x -> bf16 conversion) ----------------
__global__ void gate_kernel(const float* __restrict__ x, const float* __restrict__ gw,
                            float* __restrict__ comb, int4* __restrict__ tok_ep,
                            float2* __restrict__ tok_w, int* __restrict__ cnt,
                            int* __restrict__ list, bf16* __restrict__ xb) {
    int t = blockIdx.x;
    int lane = threadIdx.x;   // 64
    const float* xr = x + (size_t)t * H_DIM;
    float4 xv[4];
    for (int j = 0; j < 4; ++j) xv[j] = *(const float4*)(xr + lane * 4 + j * 256);
    float p[NE] = {};
    for (int e = 0; e < NE; ++e) {
        const float* wr = gw + (size_t)e * H_DIM;
        for (int j = 0; j < 4; ++j) {
            float4 wv = *(const float4*)(wr + lane * 4 + j * 256);
            p[e] += xv[j].x * wv.x + xv[j].y * wv.y + xv[j].z * wv.z + xv[j].w * wv.w;
        }
    }
    for (int j = 0; j < 4; ++j) {
        bf16x4 b = { (bf16)xv[j].x, (bf16)xv[j].y, (bf16)xv[j].z, (bf16)xv[j].w };
        *(bf16x4*)(xb + (size_t)t * H_DIM + lane * 4 + j * 256) = b;
    }
    for (int o = 32; o >= 1; o >>= 1)
        for (int e = 0; e < NE; ++e) p[e] += __shfl_xor(p[e], o);
    if (lane == 0) {
        float m = p[0];
        for (int j = 1; j < NE; ++j) m = fmaxf(m, p[j]);
        float s[NE], Z = 0.f;
        for (int j = 0; j < NE; ++j) { s[j] = expf(p[j] - m); Z += s[j]; }
        for (int j = 0; j < NE; ++j) s[j] /= Z;
        int i0 = 0;
        for (int j = 1; j < NE; ++j) if (s[j] > s[i0]) i0 = j;
        int i1 = (i0 == 0) ? 1 : 0;
        for (int j = 0; j < NE; ++j) if (j != i0 && s[j] > s[i1]) i1 = j;
        float d = s[i0] + s[i1] + 1e-20f;
        float w0 = s[i0] / d, w1 = s[i1] / d;
        for (int j = 0; j < NE; ++j) comb[t * NE + j] = 0.f;
        comb[t * NE + i0] = w0;
        comb[t * NE + i1] = w1;
        int p0 = atomicAdd(&cnt[i0], 1); list[i0 * T_TOK + p0] = t;
        int p1 = atomicAdd(&cnt[i1], 1); list[i1 * T_TOK + p1] = t;
        tok_ep[t] = make_int4(i0, p0, i1, p1);
        tok_w[t] = make_float2(w0, w1);
    }
}

__global__ void offs_kernel(const int* __restrict__ cnt, int* __restrict__ offs) {
    if (threadIdx.x == 0) {
        int a = 0;
        for (int e = 0; e < NE; ++e) { offs[e] = a; a += cnt[e]; }
        offs[NE] = a;   // routed total; shared rows start here
    }
}

// ---------------- fp32 -> bf16 conversion ----------------
__device__ inline void cvt8(const float* __restrict__ s, bf16* __restrict__ d) {
    float4 a = ((const float4*)s)[0];
    float4 b = ((const float4*)s)[1];
    bf16x8 v = { (bf16)a.x, (bf16)a.y, (bf16)a.z, (bf16)a.w,
                 (bf16)b.x, (bf16)b.y, (bf16)b.z, (bf16)b.w };
    *(bf16x8*)d = v;
}

// converts ffn1's weights only (w_down converted inside ffn1's role blocks)
__global__ void convert_kernel(const float* __restrict__ wg, const float* __restrict__ wu,
                               const float* __restrict__ wsg, const float* __restrict__ wsu,
                               bf16* wgb, bf16* wub, bf16* wsgb, bf16* wsub) {
    size_t i = ((size_t)blockIdx.x * 256 + threadIdx.x) * 8;
    if (i < N_W) { cvt8(wg + i, wgb + i); return; }
    i -= N_W;
    if (i < N_W) { cvt8(wu + i, wub + i); return; }
    i -= N_W;
    if (i < N_S) { cvt8(wsg + i, wsgb + i); return; }
    i -= N_S;
    if (i < N_S) { cvt8(wsu + i, wsub + i); }
}

#define BM 128
#define MT_MAX 104
#define BK 64
#define BK2 32
#define NH1 (H_DIM / BK2)   // 32 half-steps

// supertile map: expert-major; within expert, groups of 8 m-tiles x nt_cnt n-tiles,
// msub fastest (8 consecutive work items share a B n-tile).
__device__ inline bool map_super(const int* cnt, int bx, int nt_cnt,
                                 int& expert, int& mtile, int& nt, int& count) {
    for (int e = 0; e <= NE; ++e) {
        int c = (e < NE) ? cnt[e] : T_TOK;
        int tiles = (c + BM - 1) / BM;
        int blocks = tiles * nt_cnt;
        if (bx < blocks) {
            int full = tiles & ~7;              // m-tiles in full groups of 8
            int fullblocks = full * nt_cnt;
            int mg0, gsz, rem;
            if (bx < fullblocks) { mg0 = (bx / (nt_cnt * 8)) * 8; gsz = 8; rem = bx % (nt_cnt * 8); }
            else                 { mg0 = full; gsz = tiles - full; rem = bx - fullblocks; }
            nt = rem / gsz;
            mtile = mg0 + rem % gsz;
            expert = e; count = c;
            return true;
        }
        bx -= blocks;
    }
    return false;
}

// total active GEMM blocks (must match map_super's walk)
__device__ inline int active_blocks(const int* cnt, int nt_cnt) {
    int t = 0;
    for (int e = 0; e < NE; ++e) t += (cnt[e] + BM - 1) / BM;
    return (t + T_TOK / BM) * nt_cnt;
}

// 256-row variants for the 8-wave ffn2
#define BM8 256
#define BN8 256
#define BK8 64
#define NT2_8 (H_DIM / BN8)   // 4
#define NK2_8 (I_DIM / BK8)   // 43
#define MT256_MAX 56          // max routed tiles (<=40) + shared (16)

__device__ inline bool map_super256(const int* cnt, int bx, int nt_cnt,
                                    int& expert, int& mtile, int& nt, int& count) {
    for (int e = 0; e <= NE; ++e) {
        int c = (e < NE) ? cnt[e] : T_TOK;
        int tiles = (c + BM8 - 1) / BM8;
        int blocks = tiles * nt_cnt;
        if (bx < blocks) {
            int full = tiles & ~7;
            int fullblocks = full * nt_cnt;
            int mg0, gsz, rem;
            if (bx < fullblocks) { mg0 = (bx / (nt_cnt * 8)) * 8; gsz = 8; rem = bx % (nt_cnt * 8); }
            else                 { mg0 = full; gsz = tiles - full; rem = bx - fullblocks; }
            nt = rem / gsz;
            mtile = mg0 + rem % gsz;
            expert = e; count = c;
            return true;
        }
        bx -= blocks;
    }
    return false;
}

__device__ inline int active_blocks256(const int* cnt, int nt_cnt) {
    int t = 0;
    for (int e = 0; e < NE; ++e) t += (cnt[e] + BM8 - 1) / BM8;
    return (t + T_TOK / BM8) * nt_cnt;
}

// bijective XCD-chunked swizzle (m204 variant)
__device__ inline int xcd_chunk(int bx, int n) {
    int q = n >> 3, r = n & 7;
    int x = bx & 7, o = bx >> 3;
    return (x < r ? x * (q + 1) : r * (q + 1) + (x - r) * q) + o;
}

// linear map (slow path)
__device__ inline bool map_tile(const int* cnt, int mt, int bm,
                                int& expert, int& mtile, int& count) {
    for (int e = 0; e <= NE; ++e) {
        int c = (e < NE) ? cnt[e] : T_TOK;
        int tiles = (c + bm - 1) / bm;
        if (mt < tiles) { expert = e; mtile = mt; count = c; return true; }
        mt -= tiles;
    }
    return false;
}

// ---------------- fast GEMM1: h = silu(x@Wg^T) * (x@Wu^T) ----------------
// (round-3 structure, kept: 2-buf 32KB, BK2=32, counted vmcnt(4))
#define BN1 64
#define NT1 (I_DIM / BN1)   // 43
#define CONV1_BLKS 3096     // (N_W + N_S) / (256*32) exactly; multiple of 8

__global__ __launch_bounds__(256) void ffn1_fast(
    const bf16* __restrict__ xb, const bf16* __restrict__ wgb,
    const bf16* __restrict__ wub, const bf16* __restrict__ wsgb,
    const bf16* __restrict__ wsub, const int* __restrict__ cnt,
    const int* __restrict__ offs, const int* __restrict__ list,
    bf16* __restrict__ h,
    const float* __restrict__ wd_f, const float* __restrict__ wsd_f,
    bf16* __restrict__ wdb, bf16* __restrict__ wsdb) {
    if (blockIdx.x < CONV1_BLKS) {
        size_t base = (size_t)blockIdx.x * 8192 + (size_t)threadIdx.x * 8;
        for (int j = 0; j < 4; ++j) {
            size_t i = base + (size_t)j * 2048;
            if (i < N_W) cvt8(wd_f + i, wdb + i);
            else         cvt8(wsd_f + (i - N_W), wsdb + (i - N_W));
        }
        return;
    }
    int bx = blockIdx.x - CONV1_BLKS;   // CONV1_BLKS % 8 == 0, so bx%8 == hw XCD
    int nact = active_blocks(cnt, NT1);
    if (bx >= nact) return;
    bx = xcd_chunk(bx, nact);
    int expert, mtile, nt, count;
    if (!map_super(cnt, bx, NT1, expert, mtile, nt, count)) return;
    int rowbase = offs[expert];
    const bf16* wg = (expert < NE) ? (wgb + (size_t)expert * N_S) : wsgb;
    const bf16* wu = (expert < NE) ? (wub + (size_t)expert * N_S) : wsub;

    __shared__ bf16 As[2][BM][BK2];    // 16 KB
    __shared__ bf16 Bg[2][BN1][BK2];   // 8 KB
    __shared__ bf16 Bu[2][BN1][BK2];   // 8 KB

    int tid = threadIdx.x;
    int lane = tid & 63, wid = tid >> 6;
    int wm = wid >> 1, wn = wid & 1;
    int lr = lane & 15, lq = lane >> 4;
    int l4 = lane >> 2, c4 = lane & 3;
    int c4s = c4 ^ ((lane >> 3) & 3);   // pre-swizzled source 16B-group
    int iN = nt * BN1;

    const bf16* aptr0;
    const bf16* aptr1;
    {
        int r0 = wid * 32 + l4;
        int m0 = mtile * BM + r0;
        int t0 = 0;
        if (m0 < count) t0 = (expert < NE) ? list[expert * T_TOK + m0] : m0;
        aptr0 = xb + (size_t)t0 * H_DIM + c4s * 8;
        int r1 = wid * 32 + 16 + l4;
        int m1 = mtile * BM + r1;
        int t1 = 0;
        if (m1 < count) t1 = (expert < NE) ? list[expert * T_TOK + m1] : m1;
        aptr1 = xb + (size_t)t1 * H_DIM + c4s * 8;
    }
    int rb = wid * 16 + l4;
    const bf16* gp = wg + (size_t)(iN + rb) * H_DIM + c4s * 8;
    const bf16* up = wu + (size_t)(iN + rb) * H_DIM + c4s * 8;

    int fragoff = (lq ^ ((lr >> 1) & 3)) << 3;
    int arow[4], brow[2];
    for (int mi = 0; mi < 4; ++mi) arow[mi] = (wm * 64 + mi * 16 + lr) * BK2 + fragoff;
    for (int ni = 0; ni < 2; ++ni) brow[ni] = (wn * 32 + ni * 16 + lr) * BK2 + fragoff;

    f32x4 accg[4][2] = {};
    f32x4 accu[4][2] = {};

    auto stage = [&](int p, int hs) {   // 4 gll16 per thread
        int off = hs * BK2;
        gll16(aptr0 + off, &As[p][wid * 32][0]);
        gll16(aptr1 + off, &As[p][wid * 32 + 16][0]);
        gll16(gp + off, &Bg[p][wid * 16][0]);
        gll16(up + off, &Bu[p][wid * 16][0]);
    };

    stage(0, 0);
    int p = 0;
    for (int hs = 0; hs < NH1; ++hs) {
        int hs1 = (hs + 1 < NH1) ? hs + 1 : NH1 - 1;   // clamp keeps counts uniform
        stage(p ^ 1, hs1);
        VM_WAIT4;                        // stage(hs) landed; stage(hs+1) in flight
        __builtin_amdgcn_s_barrier();    // all waves' stage(hs) landed
        __builtin_amdgcn_sched_barrier(0);
        const bf16* Ap  = &As[p][0][0];
        const bf16* Bgp = &Bg[p][0][0];
        const bf16* Bup = &Bu[p][0][0];
        bf16x8 af[4], bgf[2], buf_[2];
        for (int mi = 0; mi < 4; ++mi) af[mi] = *(const bf16x8*)(Ap + arow[mi]);
        for (int ni = 0; ni < 2; ++ni) {
            bgf[ni]  = *(const bf16x8*)(Bgp + brow[ni]);
            buf_[ni] = *(const bf16x8*)(Bup + brow[ni]);
        }
        for (int mi = 0; mi < 4; ++mi)
            for (int ni = 0; ni < 2; ++ni) {
                accg[mi][ni] = __builtin_amdgcn_mfma_f32_16x16x32_bf16(af[mi], bgf[ni], accg[mi][ni], 0, 0, 0);
                accu[mi][ni] = __builtin_amdgcn_mfma_f32_16x16x32_bf16(af[mi], buf_[ni], accu[mi][ni], 0, 0, 0);
            }
        __builtin_amdgcn_s_barrier();    // readers done; buf p reusable next iter
        p ^= 1;
    }
    VM_DRAIN;   // pending LDS writes must not outlive the workgroup
    for (int mi = 0; mi < 4; ++mi)
        for (int ni = 0; ni < 2; ++ni)
            for (int r2 = 0; r2 < 4; ++r2) {
                int row = wm * 64 + mi * 16 + lq * 4 + r2;
                int m = mtile * BM + row;
                if (m >= count) continue;
                float g = accg[mi][ni][r2], u = accu[mi][ni][r2];
                float hv = g / (1.f + expf(-g)) * u;
                int col = iN + wn * 32 + ni * 16 + lr;
                h[(size_t)(rowbase + m) * I_DIM + col] = (bf16)hv;
            }
}

// ---------------- fast GEMM2: eo = h @ Wd^T, 256x256 tiles, BK=64, 8 waves ----------------
// Counted-vmcnt pipeline: stage tile t+1 (8 gll16/thread), vmcnt(8) waits only tile t,
// one barrier-pair per K-tile, 64 MFMA/wave per tile (4 setprio clusters of 16).
// Swizzle for 128B rows: LDS[r][g8] holds global 16B-group g8 ^ (r&7) (involution:
// pre-applied on per-lane global source; reads XOR with lr&7) -> 2-way banks (free).
__global__ __launch_bounds__(512) void ffn2_fast(
    const bf16* __restrict__ h, const bf16* __restrict__ wdb,
    const bf16* __restrict__ wsdb, const int* __restrict__ cnt,
    const int* __restrict__ offs, bf16* __restrict__ eo) {
    int nact = active_blocks256(cnt, NT2_8);
    int bx = blockIdx.x;
    if (bx >= nact) return;
    bx = xcd_chunk(bx, nact);
    int expert, mtile, nt, count;
    if (!map_super256(cnt, bx, NT2_8, expert, mtile, nt, count)) return;
    int rowbase = offs[expert];
    const bf16* wd = (expert < NE) ? (wdb + (size_t)expert * N_S) : wsdb;

    __shared__ bf16 Ab[2][BM8][BK8];   // 64 KB
    __shared__ bf16 Bb[2][BN8][BK8];   // 64 KB

    int tid = threadIdx.x;
    int lane = tid & 63, w = tid >> 6;        // 8 waves
    int wm = w >> 2, wn = w & 3;              // 2M x 4N; per-wave C: 128 x 64
    int lr = lane & 15, lq = lane >> 4;
    int l8r = lane >> 3;                      // 0..7 sub-row within 8-row chunk
    int c8 = lane & 7;
    int c8s = c8 ^ l8r;                       // pre-swizzled source 16B-group (row&7 == l8r)
    int hN = nt * BN8;

    // staging source pointers: instr j (0,1) x half hh (0,1); 8 rows per instr
    const bf16* aSrc[2][2];
    const bf16* bSrc[2][2];
    for (int j = 0; j < 2; ++j)
        for (int hh = 0; hh < 2; ++hh) {
            int r = hh * 128 + (w * 2 + j) * 8 + l8r;
            int m = mtile * BM8 + r;
            size_t arow = (size_t)rowbase + ((m < count) ? m : 0);
            aSrc[j][hh] = h + arow * I_DIM + c8s * 8;
            bSrc[j][hh] = wd + (size_t)(hN + r) * I_DIM + c8s * 8;
        }

    // fragment read offsets (elements); read-side swizzle XORs group with lr&7
    int colx[2];
    for (int ks = 0; ks < 2; ++ks) colx[ks] = (((ks * 4 + lq) ^ (lr & 7)) << 3);
    int arowoff[8], browoff[4];
    for (int mi = 0; mi < 8; ++mi) arowoff[mi] = (wm * 128 + mi * 16 + lr) * BK8;
    for (int ni = 0; ni < 4; ++ni) browoff[ni] = (wn * 64 + ni * 16 + lr) * BK8;

    f32x4 acc[8][4] = {};

    auto stage = [&](int b, int t) {   // 8 gll16 per thread (one K-tile: A + B)
        int off = t * BK8;
        for (int hh = 0; hh < 2; ++hh)
            for (int j = 0; j < 2; ++j) {
                gll16(aSrc[j][hh] + off, &Ab[b][hh * 128 + (w * 2 + j) * 8][0]);
                gll16(bSrc[j][hh] + off, &Bb[b][hh * 128 + (w * 2 + j) * 8][0]);
            }
    };

    stage(0, 0);
    for (int t = 0; t < NK2_8; ++t) {
        int tn = (t + 1 < NK2_8) ? t + 1 : t;   // clamp keeps ledger uniform
        stage((t + 1) & 1, tn);                 // safe: prev readers of this buf gated by last end-barrier
        VM_WAIT8;                               // tile t landed; tile t+1's 8 loads stay in flight
        __builtin_amdgcn_s_barrier();
        __builtin_amdgcn_sched_barrier(0);
        const bf16* Ap = &Ab[t & 1][0][0];
        const bf16* Bp = &Bb[t & 1][0][0];
        bf16x8 bfr[4][2];
        for (int ni = 0; ni < 4; ++ni)
            for (int ks = 0; ks < 2; ++ks)
                bfr[ni][ks] = *(const bf16x8*)(Bp + browoff[ni] + colx[ks]);
        for (int mp = 0; mp < 4; ++mp) {
            bf16x8 afr[2][2];
            for (int m2 = 0; m2 < 2; ++m2)
                for (int ks = 0; ks < 2; ++ks)
                    afr[m2][ks] = *(const bf16x8*)(Ap + arowoff[mp * 2 + m2] + colx[ks]);
            __builtin_amdgcn_s_setprio(1);
            for (int m2 = 0; m2 < 2; ++m2)
                for (int ni = 0; ni < 4; ++ni)
                    for (int ks = 0; ks < 2; ++ks)
                        acc[mp * 2 + m2][ni] = __builtin_amdgcn_mfma_f32_16x16x32_bf16(
                            afr[m2][ks], bfr[ni][ks], acc[mp * 2 + m2][ni], 0, 0, 0);
            __builtin_amdgcn_s_setprio(0);
        }
        __builtin_amdgcn_s_barrier();           // all reads of buf[t&1] done -> next stage safe
        __builtin_amdgcn_sched_barrier(0);
    }
    VM_DRAIN;   // pending LDS writes must not outlive the workgroup
    for (int mi = 0; mi < 8; ++mi)
        for (int ni = 0; ni < 4; ++ni)
            for (int r2 = 0; r2 < 4; ++r2) {
                int row = wm * 128 + mi * 16 + lq * 4 + r2;
                int m = mtile * BM8 + row;
                if (m >= count) continue;
                int col = hN + wn * 64 + ni * 16 + lr;
                eo[(size_t)(rowbase + m) * H_DIM + col] = (bf16)acc[mi][ni][r2];
            }
}

// ---------------- combine: out[t] = w0*eo[r0] + w1*eo[r1] + eo[shared_t] ----------------
__global__ __launch_bounds__(256) void combine_kernel(
    const bf16* __restrict__ eo, const int* __restrict__ offs,
    const int4* __restrict__ tok_ep, const float2* __restrict__ tok_w,
    float* __restrict__ out) {
    int t = blockIdx.x;
    int c = threadIdx.x * 4;
    int4 ep = tok_ep[t];
    float2 w = tok_w[t];
    size_t r0 = (size_t)(offs[ep.x] + ep.y) * H_DIM + c;
    size_t r1 = (size_t)(offs[ep.z] + ep.w) * H_DIM + c;
    size_t rs = (size_t)(offs[NE] + t) * H_DIM + c;
    bf16x4 a = *(const bf16x4*)(eo + r0);
    bf16x4 b = *(const bf16x4*)(eo + r1);
    bf16x4 s = *(const bf16x4*)(eo + rs);
    float4 o;
    o.x = w.x * (float)a[0] + w.y * (float)b[0] + (float)s[0];
    o.y = w.x * (float)a[1] + w.y * (float)b[1] + (float)s[1];
    o.z = w.x * (float)a[2] + w.y * (float)b[2] + (float)s[2];
    o.w = w.x * (float)a[3] + w.y * (float)b[3] + (float)s[3];
    *(float4*)(out + (size_t)t * H_DIM + c) = o;
}

// ================= slow fallback (fp32 staging, atomics) =================
#define SBN1 64
#define SNT1 (I_DIM / SBN1)
#define SBN2 64
#define SNT2 (H_DIM / SBN2)

__global__ __launch_bounds__(256) void ffn1_slow(
    const float* __restrict__ x, const float* __restrict__ w_gate,
    const float* __restrict__ w_up, const float* __restrict__ wsg,
    const float* __restrict__ wsu, const int* __restrict__ cnt,
    const int* __restrict__ offs, const int* __restrict__ list,
    bf16* __restrict__ h) {
    int nt = blockIdx.x % SNT1;
    int mt = blockIdx.x / SNT1;
    int expert, mtile, count;
    if (!map_tile(cnt, mt, BM, expert, mtile, count)) return;
    int rowbase = offs[expert];
    const float* wg = (expert < NE) ? (w_gate + (size_t)expert * N_S) : wsg;
    const float* wu = (expert < NE) ? (w_up + (size_t)expert * N_S) : wsu;
    __shared__ bf16 As[BM][BK + 8];
    __shared__ bf16 Bg[SBN1][BK + 8];
    __shared__ bf16 Bu[SBN1][BK + 8];
    int tid = threadIdx.x;
    int lane = tid & 63, wid = tid >> 6;
    int wm = wid >> 1, wn = wid & 1;
    int lr = lane & 15, lq = lane >> 4;
    int cg = tid & 15;
    int iN = nt * SBN1;
    int arow_tok[8];
    for (int p2 = 0; p2 < 8; ++p2) {
        int r = (tid >> 4) + p2 * 16;
        int m = mtile * BM + r;
        arow_tok[p2] = (m < count) ? ((expert < NE) ? list[expert * T_TOK + m] : m) : -1;
    }
    f32x4 accg[4][2] = {};
    f32x4 accu[4][2] = {};
    for (int kt = 0; kt < H_DIM; kt += BK) {
        for (int p2 = 0; p2 < 8; ++p2) {
            int r = (tid >> 4) + p2 * 16;
            int tok = arow_tok[p2];
            float4 v = make_float4(0.f, 0.f, 0.f, 0.f);
            if (tok >= 0) v = *(const float4*)(x + (size_t)tok * H_DIM + kt + cg * 4);
            bf16* dst = &As[r][cg * 4];
            dst[0] = (bf16)v.x; dst[1] = (bf16)v.y; dst[2] = (bf16)v.z; dst[3] = (bf16)v.w;
        }
        for (int p2 = 0; p2 < 4; ++p2) {
            int r = (tid >> 4) + p2 * 16;
            float4 vg = *(const float4*)(wg + (size_t)(iN + r) * H_DIM + kt + cg * 4);
            float4 vu = *(const float4*)(wu + (size_t)(iN + r) * H_DIM + kt + cg * 4);
            bf16* dg = &Bg[r][cg * 4];
            dg[0] = (bf16)vg.x; dg[1] = (bf16)vg.y; dg[2] = (bf16)vg.z; dg[3] = (bf16)vg.w;
            bf16* du = &Bu[r][cg * 4];
            du[0] = (bf16)vu.x; du[1] = (bf16)vu.y; du[2] = (bf16)vu.z; du[3] = (bf16)vu.w;
        }
        __syncthreads();
        for (int kk = 0; kk < BK; kk += 32) {
            bf16x8 af[4], bgf[2], buf2[2];
            for (int mi = 0; mi < 4; ++mi)
                af[mi] = *(const bf16x8*)&As[wm * 64 + mi * 16 + lr][kk + lq * 8];
            for (int ni = 0; ni < 2; ++ni) {
                bgf[ni] = *(const bf16x8*)&Bg[wn * 32 + ni * 16 + lr][kk + lq * 8];
                buf2[ni] = *(const bf16x8*)&Bu[wn * 32 + ni * 16 + lr][kk + lq * 8];
            }
            for (int mi = 0; mi < 4; ++mi)
                for (int ni = 0; ni < 2; ++ni) {
                    accg[mi][ni] = __builtin_amdgcn_mfma_f32_16x16x32_bf16(af[mi], bgf[ni], accg[mi][ni], 0, 0, 0);
                    accu[mi][ni] = __builtin_amdgcn_mfma_f32_16x16x32_bf16(af[mi], buf2[ni], accu[mi][ni], 0, 0, 0);
                }
        }
        __syncthreads();
    }
    for (int mi = 0; mi < 4; ++mi)
        for (int ni = 0; ni < 2; ++ni)
            for (int r2 = 0; r2 < 4; ++r2) {
                int row = wm * 64 + mi * 16 + lq * 4 + r2;
                int m = mtile * BM + row;
                if (m >= count) continue;
                float g = accg[mi][ni][r2], u = accu[mi][ni][r2];
                float hv = g / (1.f + expf(-g)) * u;
                int col = iN + wn * 32 + ni * 16 + lr;
                h[(size_t)(rowbase + m) * I_DIM + col] = (bf16)hv;
            }
}

__global__ __launch_bounds__(256) void ffn2_slow(
    const bf16* __restrict__ h, const float* __restrict__ w_down,
    const float* __restrict__ wsd, const int* __restrict__ cnt,
    const int* __restrict__ offs, const int* __restrict__ list,
    const float* __restrict__ comb, float* __restrict__ out) {
    int nt = blockIdx.x % SNT2;
    int mt = blockIdx.x / SNT2;
    int expert, mtile, count;
    if (!map_tile(cnt, mt, BM, expert, mtile, count)) return;
    int rowbase = offs[expert];
    const float* wd = (expert < NE) ? (w_down + (size_t)expert * N_S) : wsd;
    __shared__ bf16 As[BM][BK + 8];
    __shared__ bf16 Bs[SBN2][BK + 8];
    int tid = threadIdx.x;
    int lane = tid & 63, wid = tid >> 6;
    int wm = wid >> 1, wn = wid & 1;
    int lr = lane & 15, lq = lane >> 4;
    int hN = nt * SBN2;
    int arow_m[4];
    for (int p2 = 0; p2 < 4; ++p2) {
        int r = (tid >> 3) + p2 * 32;
        int m = mtile * BM + r;
        arow_m[p2] = (m < count) ? m : -1;
    }
    f32x4 acc[4][2] = {};
    for (int kt = 0; kt < I_DIM; kt += BK) {
        for (int p2 = 0; p2 < 4; ++p2) {
            int r = (tid >> 3) + p2 * 32;
            int m = arow_m[p2];
            float4 v = make_float4(0.f, 0.f, 0.f, 0.f);
            if (m >= 0) v = *(const float4*)(h + (size_t)(rowbase + m) * I_DIM + kt + (tid & 7) * 8);
            *(float4*)&As[r][(tid & 7) * 8] = v;
        }
        for (int p2 = 0; p2 < 4; ++p2) {
            int r = (tid >> 4) + p2 * 16;
            float4 v = *(const float4*)(wd + (size_t)(hN + r) * I_DIM + kt + (tid & 15) * 4);
            bf16* d = &Bs[r][(tid & 15) * 4];
            d[0] = (bf16)v.x; d[1] = (bf16)v.y; d[2] = (bf16)v.z; d[3] = (bf16)v.w;
        }
        __syncthreads();
        for (int kk = 0; kk < BK; kk += 32) {
            bf16x8 af[4], bf2[2];
            for (int mi = 0; mi < 4; ++mi)
                af[mi] = *(const bf16x8*)&As[wm * 64 + mi * 16 + lr][kk + lq * 8];
            for (int ni = 0; ni < 2; ++ni)
                bf2[ni] = *(const bf16x8*)&Bs[wn * 32 + ni * 16 + lr][kk + lq * 8];
            for (int mi = 0; mi < 4; ++mi)
                for (int ni = 0; ni < 2; ++ni)
                    acc[mi][ni] = __builtin_amdgcn_mfma_f32_16x16x32_bf16(af[mi], bf2[ni], acc[mi][ni], 0, 0, 0);
        }
        __syncthreads();
    }
    for (int mi = 0; mi < 4; ++mi)
        for (int ni = 0; ni < 2; ++ni)
            for (int r2 = 0; r2 < 4; ++r2) {
                int row = wm * 64 + mi * 16 + lq * 4 + r2;
                int m = mtile * BM + row;
                if (m >= count) continue;
                int tok; float wgt;
                if (expert < NE) {
                    tok = list[expert * T_TOK + m];
                    wgt = comb[tok * NE + expert];
                } else {
                    tok = m;
                    wgt = 1.f;
                }
                int col = hN + wn * 32 + ni * 16 + lr;
                atomicAdd(&out[(size_t)tok * H_DIM + col], wgt * acc[mi][ni][r2]);
            }
}

extern "C" void kernel_launch(void* const* d_in, const int* in_sizes, int n_in,
                              void* d_out, int out_size, void* d_ws, size_t ws_size,
                              hipStream_t stream) {
    (void)in_sizes; (void)n_in; (void)out_size;
    const float* x      = (const float*)d_in[0];
    const float* gate_w = (const float*)d_in[1];
    const float* w_gate = (const float*)d_in[2];
    const float* w_up   = (const float*)d_in[3];
    const float* w_down = (const float*)d_in[4];
    const float* wsg    = (const float*)d_in[5];
    const float* wsu    = (const float*)d_in[6];
    const float* wsd    = (const float*)d_in[7];
    float* out = (float*)d_out;
    char* ws = (char*)d_ws;
    int*    cnt    = (int*)(ws + WS_CNT);
    int*    offs   = (int*)(ws + WS_OFFS);
    float*  comb   = (float*)(ws + WS_COMB);
    int4*   tok_ep = (int4*)(ws + WS_TOKEP);
    float2* tok_w  = (float2*)(ws + WS_TOKW);
    int*    list   = (int*)(ws + WS_LIST);
    bf16*   xb     = (bf16*)(ws + WS_XB);

    hipMemsetAsync(cnt, 0, 64, stream);
    gate_kernel<<<T_TOK, 64, 0, stream>>>(x, gate_w, comb, tok_ep, tok_w, cnt, list, xb);
    offs_kernel<<<1, 64, 0, stream>>>(cnt, offs);

    if (ws_size >= WS_NEED) {
        bf16* wgb  = (bf16*)(ws + WS_WGB);
        bf16* wub  = (bf16*)(ws + WS_WUB);
        bf16* wdb  = (bf16*)(ws + WS_WDB);
        bf16* wsgb = (bf16*)(ws + WS_WSGB);
        bf16* wsub = (bf16*)(ws + WS_WSUB);
        bf16* wsdb = (bf16*)(ws + WS_WSDB);
        bf16* h    = (bf16*)(ws + WS_HF);
        bf16* eo   = (bf16*)(ws + WS_EO);    // aliases wgb (dead after ffn1)
        size_t total8 = (2 * N_W + 2 * N_S) / 8;     // wg, wu, wsg, wsu
        int cblocks = (int)((total8 + 255) / 256);   // 24768
        convert_kernel<<<cblocks, 256, 0, stream>>>(w_gate, w_up, wsg, wsu,
                                                    wgb, wub, wsgb, wsub);
        ffn1_fast<<<CONV1_BLKS + MT_MAX * NT1, 256, 0, stream>>>(
            xb, wgb, wub, wsgb, wsub, cnt, offs, list, h,
            w_down, wsd, wdb, wsdb);
        ffn2_fast<<<MT256_MAX * NT2_8, 512, 0, stream>>>(h, wdb, wsdb, cnt, offs, eo);
        combine_kernel<<<T_TOK, 256, 0, stream>>>(eo, offs, tok_ep, tok_w, out);
    } else {
        bf16* h = (bf16*)(ws + WS_HS);
        hipMemsetAsync(out, 0, (size_t)T_TOK * H_DIM * sizeof(float), stream);
        ffn1_slow<<<MT_MAX * SNT1, 256, 0, stream>>>(x, w_gate, w_up, wsg, wsu, cnt, offs, list, h);
        ffn2_slow<<<MT_MAX * SNT2, 256, 0, stream>>>(h, w_down, wsd, cnt, offs, list, comb, out);
    }
}